// Round 3
// baseline (12827.879 us; speedup 1.0000x reference)
//
#include <hip/hip_runtime.h>
#include <math.h>

// Seq2SeqRNN fp32.
// Encoder recurrence: 256 WGs (1/CU), h staged to LDS each step, RMW-free
// flag barriers (release store + acquire poll, monotonic values).
// Decoder: per step ONE fused kernel (att+gru1+gru2, 76 WGs, 2 in-kernel
// barriers) + one logit/argmax kernel (k-split, embT read once).

#define DINL static __device__ __forceinline__

DINL float sigm(float x) { return 1.0f / (1.0f + expf(-x)); }
DINL float dot4f(float4 a, float4 b) { return a.x*b.x + a.y*b.y + a.z*b.z + a.w*b.w; }

DINL unsigned long long packmax(float x, int v) {
  unsigned u = __float_as_uint(x);
  u = (u & 0x80000000u) ? ~u : (u | 0x80000000u);
  return ((unsigned long long)u << 32) | (unsigned)(~v);  // ties -> smaller v wins
}
DINL unsigned long long umax64(unsigned long long a, unsigned long long b) {
  return a > b ? a : b;
}

// group barrier: self-flag release store, poll n flags (stride 32 ints), target value
DINL void flagbar(int* flags, int selfid, int n, int target, int tid) {
  __syncthreads();
  if (tid == 0)
    __hip_atomic_store(&flags[selfid * 32], target, __ATOMIC_RELEASE, __HIP_MEMORY_SCOPE_AGENT);
  for (int i = tid; i < n; i += 256) {
    while (__hip_atomic_load(&flags[i * 32], __ATOMIC_ACQUIRE, __HIP_MEMORY_SCOPE_AGENT) < target)
      __builtin_amdgcn_s_sleep(1);
  }
  __syncthreads();
}

// ---------------- embedding gather (300 = 75 float4)
__global__ __launch_bounds__(256) void k_embed(const float4* __restrict__ E,
                                               const int* __restrict__ inp,
                                               float4* __restrict__ out) {
  int i = blockIdx.x * 256 + threadIdx.x;
  if (i >= 8192 * 75) return;
  int row = i / 75, q = i - row * 75;
  out[i] = E[(size_t)inp[row] * 75 + q];
}

// ---------------- transpose B[c*R+r] = A[r*C+c]
__global__ __launch_bounds__(256) void k_transpose(const float* __restrict__ A,
                                                   float* __restrict__ B, int R, int C) {
  __shared__ float tile[32][33];
  int c0 = blockIdx.x * 32, r0 = blockIdx.y * 32;
  int tx = threadIdx.x & 31, ty = threadIdx.x >> 5;
  for (int i = 0; i < 32; i += 8) {
    int r = r0 + ty + i, c = c0 + tx;
    if (r < R && c < C) tile[ty + i][tx] = A[(size_t)r * C + c];
  }
  __syncthreads();
  for (int i = 0; i < 32; i += 8) {
    int c = c0 + ty + i, r = r0 + tx;
    if (c < C && r < R) B[(size_t)c * R + r] = tile[tx][ty + i];
  }
}

// ---------------- fp32 GEMM-NT: C[n,m] = sum_k A[n,k]*B[m,k] + bias[m]
__global__ __launch_bounds__(256) void k_gemm128(const float* __restrict__ A,
                                                 const float* __restrict__ B,
                                                 const float* __restrict__ bias,
                                                 float* __restrict__ C,
                                                 int N, int M, int K) {
  __shared__ float As[8][132];
  __shared__ float Bs[8][132];
  const int tid = threadIdx.x;
  const int bn = blockIdx.x * 128, bm = blockIdx.y * 128;
  const int tn = (tid >> 4) << 3, tm = (tid & 15) << 3;
  const int r = tid & 127;
  const bool isB = tid >= 128;
  const float* src = isB ? (B + (size_t)(bm + r) * K) : (A + (size_t)(bn + r) * K);
  const bool rowok = isB ? (bm + r < M) : (bn + r < N);
  float acc[8][8] = {};
  for (int k0 = 0; k0 < K; k0 += 8) {
    float v[8];
    if (rowok && k0 + 8 <= K) {
      float4 p0 = *(const float4*)(src + k0);
      float4 p1 = *(const float4*)(src + k0 + 4);
      v[0]=p0.x; v[1]=p0.y; v[2]=p0.z; v[3]=p0.w;
      v[4]=p1.x; v[5]=p1.y; v[6]=p1.z; v[7]=p1.w;
    } else {
#pragma unroll
      for (int j = 0; j < 8; ++j) v[j] = (rowok && k0 + j < K) ? src[k0 + j] : 0.0f;
    }
    float (*dst)[132] = isB ? Bs : As;
#pragma unroll
    for (int j = 0; j < 8; ++j) dst[j][r] = v[j];
    __syncthreads();
#pragma unroll
    for (int kk = 0; kk < 8; ++kk) {
      float a[8], b[8];
      *(float4*)&a[0] = *(const float4*)&As[kk][tn];
      *(float4*)&a[4] = *(const float4*)&As[kk][tn + 4];
      *(float4*)&b[0] = *(const float4*)&Bs[kk][tm];
      *(float4*)&b[4] = *(const float4*)&Bs[kk][tm + 4];
#pragma unroll
      for (int i = 0; i < 8; ++i)
#pragma unroll
        for (int j = 0; j < 8; ++j) acc[i][j] += a[i] * b[j];
    }
    __syncthreads();
  }
#pragma unroll
  for (int i = 0; i < 8; ++i) {
    int row = bn + tn + i;
    if (row >= N) continue;
#pragma unroll
    for (int j = 0; j < 8; ++j) {
      int col = bm + tm + j;
      if (col < M) C[(size_t)row * M + col] = acc[i][j] + (bias ? bias[col] : 0.0f);
    }
  }
}

// ---------------- persistent encoder layer.
// grid (16 cgrp, 8 bgrp, 2 dir) = 256 WGs. WG: 16 cols x 8 batches x 2 kslices.
// Barrier group: 16 WGs sharing (dir, bgrp). h staged to LDS each step.
__global__ __launch_bounds__(256) void k_enc_layer(
    const float* __restrict__ giF, const float* __restrict__ giB,
    const float* __restrict__ Whh,   // [2][768][256]
    const float* __restrict__ bhh,   // [2][768]
    float* __restrict__ y,           // [128][64][512]
    float* __restrict__ hbuf,        // [2 pp][2 dir][64][256]
    int* __restrict__ flags) {       // [16 groups][16 wg][32]
  const int dir = blockIdx.z;
  const int c0 = blockIdx.x << 4;
  const int b0 = blockIdx.y << 3;
  const int tid = threadIdx.x;
  const int cl = tid >> 4;            // 0..15
  const int bl = (tid >> 1) & 7;      // 0..7
  const int ks = tid & 1;
  const float* gi = dir ? giB : giF;
  const float* W = Whh + (size_t)dir * 196608;
  const float* bh = bhh + dir * 768;
  float* hb = hbuf + dir * 16384;
  int* myflags = flags + ((dir << 3) + blockIdx.y) * 16 * 32;

  __shared__ __align__(16) float W0[16][260], W1[16][260], W2[16][260];
  __shared__ __align__(16) float hsh[8][260];

  for (int i = tid; i < 48 * 64; i += 256) {
    int row = i >> 6, q = i & 63;
    int g = row >> 4, rc = row & 15;
    float4 w = ((const float4*)W)[(size_t)(c0 + rc + (g << 8)) * 64 + q];
    float* dst = (g == 0) ? &W0[rc][0] : ((g == 1) ? &W1[rc][0] : &W2[rc][0]);
    *(float4*)&dst[q << 2] = w;
  }
  __syncthreads();

  const int b = b0 + bl, c = c0 + cl;
  const float bhr = bh[c], bhz = bh[256 + c], bhn = bh[512 + c];
  const int kbase = ks << 7;

  // prefetch gi(t=0)
  {
    const int tt0 = dir ? 127 : 0;
    const float* gp = gi + (size_t)tt0 * 49152 + (size_t)b * 768;
    // fallthrough into loop-carried regs
    float gr0 = gp[c], gz0 = gp[256 + c], gn0 = gp[512 + c];
    float gr = gr0, gz = gz0, gn = gn0;

    for (int t = 0; t < 128; ++t) {
      const int pp = t & 1;
      // stage h (this group's 8 batches, full 256 cols) into LDS
      {
        const float* hsrc = hb + pp * 32768 + (b0 << 8);
        int i0 = tid, b1 = i0 >> 6, k1 = i0 & 63;
        int i1 = tid + 256, b2 = i1 >> 6, k2 = i1 & 63;
        float4 h0 = *(const float4*)(hsrc + (b1 << 8) + (k1 << 2));
        float4 h1 = *(const float4*)(hsrc + (b2 << 8) + (k2 << 2));
        *(float4*)&hsh[b1][k1 << 2] = h0;
        *(float4*)&hsh[b2][k2 << 2] = h1;
      }
      __syncthreads();

      // prefetch next gi (hides latency under the dot loop)
      float nr = 0.f, nz = 0.f, nn = 0.f;
      if (t < 127) {
        const int tn_ = dir ? 126 - t : t + 1;
        const float* gp2 = gi + (size_t)tn_ * 49152 + (size_t)b * 768;
        nr = gp2[c]; nz = gp2[256 + c]; nn = gp2[512 + c];
      }

      float ar = 0.f, az = 0.f, an = 0.f;
#pragma unroll 8
      for (int kq = 0; kq < 32; ++kq) {
        const int k = kbase + (kq << 2);
        float4 hv = *(const float4*)&hsh[bl][k];
        ar += dot4f(hv, *(const float4*)&W0[cl][k]);
        az += dot4f(hv, *(const float4*)&W1[cl][k]);
        an += dot4f(hv, *(const float4*)&W2[cl][k]);
      }
      ar += __shfl_xor(ar, 1);
      az += __shfl_xor(az, 1);
      an += __shfl_xor(an, 1);

      float rg = sigm(gr + ar + bhr);
      float zg = sigm(gz + az + bhz);
      float ng = tanhf(gn + rg * (an + bhn));
      float hnew = (1.f - zg) * ng + zg * hsh[bl][c];

      if (ks == 0) {
        const int tt = dir ? 127 - t : t;
        hb[(pp ^ 1) * 32768 + (b << 8) + c] = hnew;
        y[(size_t)tt * 32768 + (b << 9) + (dir << 8) + c] = hnew;
      }
      gr = nr; gz = nz; gn = nn;

      if (t < 127) flagbar(myflags, blockIdx.x, 16, t + 1, tid);
    }
  }
}

// ---------------- hcat[2][64][512]
__global__ __launch_bounds__(256) void k_hcat(const float* __restrict__ x1,
                                              const float* __restrict__ encout,
                                              float* __restrict__ hcat) {
  int i = blockIdx.x * 256 + threadIdx.x;  // 65536
  int l = i >> 15, r = i & 32767, b = r >> 9, d = r & 511;
  const float* src = l ? encout : x1;
  int ts = (d < 256) ? 127 : 0;
  hcat[i] = src[((size_t)(ts << 6) + b) * 512 + d];
}

// ---------------- decoder GRU cell body (300/300), cb in [0,76)
DINL void gru_phase(int cb, int tid, const float* __restrict__ xin,
                    const float* __restrict__ hin, float* __restrict__ hout,
                    float* __restrict__ houtT,
                    const float* __restrict__ Wih, const float* __restrict__ Whh,
                    const float* __restrict__ bih, const float* __restrict__ bhh,
                    float* xs, float* hs) {  // xs,hs: 16*300 each
  const int cchunk = cb % 19, bchunk = cb / 19;
  const int cl = tid & 15, bl = tid >> 4;
  const int c = cchunk * 16 + cl;
  const int b0 = bchunk * 16, bq = b0 + bl;
  for (int i = tid; i < 16 * 75; i += 256) {
    int row = i / 75, q = i - row * 75;
    ((float4*)(xs + row * 300))[q] = ((const float4*)(xin + (size_t)(b0 + row) * 300))[q];
    ((float4*)(hs + row * 300))[q] = ((const float4*)(hin + (size_t)(b0 + row) * 300))[q];
  }
  __syncthreads();
  if (c < 300) {
    float gir = bih[c], giz = bih[300 + c], gin = bih[600 + c];
    float ghr = bhh[c], ghz = bhh[300 + c], ghn = bhh[600 + c];
    const float4* wir = (const float4*)(Wih + (size_t)c * 300);
    const float4* wiz = (const float4*)(Wih + (size_t)(300 + c) * 300);
    const float4* win = (const float4*)(Wih + (size_t)(600 + c) * 300);
    const float4* whr = (const float4*)(Whh + (size_t)c * 300);
    const float4* whz = (const float4*)(Whh + (size_t)(300 + c) * 300);
    const float4* whn = (const float4*)(Whh + (size_t)(600 + c) * 300);
    const float4* xr = (const float4*)(xs + bl * 300);
    const float4* hr = (const float4*)(hs + bl * 300);
    for (int q = 0; q < 75; ++q) {
      float4 xv = xr[q], hv = hr[q];
      gir += dot4f(xv, wir[q]);
      giz += dot4f(xv, wiz[q]);
      gin += dot4f(xv, win[q]);
      ghr += dot4f(hv, whr[q]);
      ghz += dot4f(hv, whz[q]);
      ghn += dot4f(hv, whn[q]);
    }
    float r = sigm(gir + ghr), z = sigm(giz + ghz);
    float n = tanhf(gin + r * ghn);
    float hnew = (1.f - z) * n + z * hs[bl * 300 + c];
    hout[(size_t)bq * 300 + c] = hnew;
    if (houtT) houtT[(size_t)c * 64 + bq] = hnew;
  }
}

// ---------------- fused decoder step: att (WG<64) | bar | gru1 | bar | gru2
__global__ __launch_bounds__(256) void k_dec_step(
    const float* __restrict__ hc, float* __restrict__ hn, float* __restrict__ h1T,
    const float* __restrict__ w1e, const float* __restrict__ encout,
    const float* __restrict__ l2W, const float* __restrict__ l2b,
    const float* __restrict__ l3W, const float* __restrict__ l3b,
    const float* __restrict__ Vatt, const float* __restrict__ embdec,
    const float* __restrict__ dWih, const float* __restrict__ dWhh,
    const float* __restrict__ dbih, const float* __restrict__ dbhh,
    const unsigned long long* __restrict__ prev,  // null at t=0, else bests[250][64]
    float* __restrict__ xdec, int* __restrict__ flags, int tstep) {
  const int tid = threadIdx.x, cb = blockIdx.x;
  __shared__ __align__(16) float smem[9600];
  float* h1s = smem;                 // 300 (+4)
  float* w2h = smem + 304;           // 300 (+4)
  float* eXa = smem + 608;           // 812 (+4)
  float* aa  = smem + 1424;          // 128
  float* red = smem + 1552;          // 128
  unsigned long long* redb = (unsigned long long*)(smem + 1680);  // 128 u64

  if (cb < 64) {
    const int b = cb;
    const float* h1 = hc + 19200;
    if (tid < 128) {
      unsigned long long m = 0ULL;
      if (prev) {
        m = prev[(size_t)tid * 64 + b];
        if (tid < 122) m = umax64(m, prev[(size_t)(tid + 128) * 64 + b]);
      }
      redb[tid] = m;
    }
    for (int i = tid; i < 300; i += 256) h1s[i] = h1[b * 300 + i];
    __syncthreads();
    for (int s = 64; s > 0; s >>= 1) {
      if (tid < s) redb[tid] = umax64(redb[tid], redb[tid + s]);
      __syncthreads();
    }
    const int ib = prev ? (int)(~(unsigned)(redb[0] & 0xFFFFFFFFULL)) : 0;

    for (int m = tid; m < 300; m += 256) {
      const float4* wr = (const float4*)(l2W + (size_t)m * 300);
      const float4* hr = (const float4*)h1s;
      float acc = l2b[m];
      for (int q = 0; q < 75; ++q) acc += dot4f(wr[q], hr[q]);
      w2h[m] = acc;
    }
    __syncthreads();

    if (tid < 128) {
      const float4* wp = (const float4*)(w1e + ((size_t)(tid << 6) + b) * 300);
      const float4* vp = (const float4*)Vatt;
      const float4* hp = (const float4*)w2h;
      float acc = 0.f;
      for (int q = 0; q < 75; ++q) {
        float4 w = wp[q], h = hp[q], v = vp[q];
        acc += tanhf(w.x + h.x) * v.x + tanhf(w.y + h.y) * v.y +
               tanhf(w.z + h.z) * v.z + tanhf(w.w + h.w) * v.w;
      }
      aa[tid] = acc;
      red[tid] = acc;
    }
    __syncthreads();
    for (int s = 64; s > 0; s >>= 1) {
      if (tid < s) red[tid] = fmaxf(red[tid], red[tid + s]);
      __syncthreads();
    }
    float mx = red[0];
    __syncthreads();
    if (tid < 128) {
      float ex = expf(aa[tid] - mx);
      aa[tid] = ex;
      red[tid] = ex;
    }
    __syncthreads();
    for (int s = 64; s > 0; s >>= 1) {
      if (tid < s) red[tid] += red[tid + s];
      __syncthreads();
    }
    float inv = 1.0f / red[0];
    __syncthreads();
    if (tid < 128) aa[tid] *= inv;
    for (int d = tid; d < 300; d += 256) eXa[d] = embdec[(size_t)ib * 300 + d];
    __syncthreads();

    for (int d = tid; d < 512; d += 256) {
      float acc = 0.f;
      for (int s = 0; s < 128; ++s) acc += aa[s] * encout[((size_t)(s << 6) + b) * 512 + d];
      eXa[300 + d] = acc;
    }
    __syncthreads();

    for (int m = tid; m < 300; m += 256) {
      const float4* wr = (const float4*)(l3W + (size_t)m * 812);
      const float4* xr = (const float4*)eXa;
      float acc = l3b[m];
      for (int q = 0; q < 203; ++q) acc += dot4f(wr[q], xr[q]);
      xdec[b * 300 + m] = acc;
    }
  }

  flagbar(flags, cb, 76, 2 * tstep + 1, tid);
  gru_phase(cb, tid, xdec, hc, hn, nullptr, dWih, dWhh, dbih, dbhh,
            smem, smem + 4800);
  flagbar(flags, cb, 76, 2 * tstep + 2, tid);
  gru_phase(cb, tid, hn, hc + 19200, hn + 19200, h1T,
            dWih + 270000, dWhh + 270000, dbih + 900, dbhh + 900,
            smem, smem + 4800);
}

// ---------------- logits + fused argmax partials. grid 250; block = 128 v x 2 khalf.
__global__ __launch_bounds__(256) void k_dec_out(const float* __restrict__ embT,
                                                 const float* __restrict__ h1T,
                                                 const float* __restrict__ outb,
                                                 float* __restrict__ out,
                                                 unsigned long long* __restrict__ bests) {
  const int tid = threadIdx.x;
  const int vt = tid & 127, kh = tid >> 7;
  const int v = blockIdx.x * 128 + vt;
  __shared__ float sacc[128][65];
  float acc[64];
#pragma unroll
  for (int i = 0; i < 64; ++i) acc[i] = 0.f;
  const int kb = kh * 150;
  for (int k = kb; k < kb + 150; ++k) {
    float ev = embT[(size_t)k * 32000 + v];
    const float* h = h1T + k * 64;
#pragma unroll
    for (int i = 0; i < 64; ++i) acc[i] += ev * h[i];
  }
  if (kh) {
#pragma unroll
    for (int i = 0; i < 64; ++i) sacc[vt][i] = acc[i];
  }
  __syncthreads();
  if (!kh) {
    float bo = outb[v];
#pragma unroll
    for (int i = 0; i < 64; ++i) {
      float val = acc[i] + sacc[vt][i] + bo;
      out[(size_t)i * 32000 + v] = val;
      sacc[vt][i] = val;
    }
  }
  __syncthreads();
  if (tid < 64) {
    unsigned long long best = 0ULL;
    const int v0 = blockIdx.x * 128;
    for (int q = 0; q < 128; ++q)
      best = umax64(best, packmax(sacc[q][tid], v0 + q));
    bests[(size_t)blockIdx.x * 64 + tid] = best;
  }
}

extern "C" void kernel_launch(void* const* d_in, const int* in_sizes, int n_in,
                              void* d_out_v, int out_size, void* d_ws, size_t ws_size,
                              hipStream_t stream) {
  (void)in_sizes; (void)n_in; (void)out_size; (void)ws_size;
  const float* emb_enc = (const float*)d_in[0];
  const float* eWih0   = (const float*)d_in[1];
  const float* eWhh0   = (const float*)d_in[2];
  const float* ebih0   = (const float*)d_in[3];
  const float* ebhh0   = (const float*)d_in[4];
  const float* eWih1   = (const float*)d_in[5];
  const float* eWhh1   = (const float*)d_in[6];
  const float* ebih1   = (const float*)d_in[7];
  const float* ebhh1   = (const float*)d_in[8];
  const float* Wout    = (const float*)d_in[9];
  const float* emb_dec = (const float*)d_in[10];
  const float* dWih    = (const float*)d_in[11];
  const float* dWhh    = (const float*)d_in[12];
  const float* dbih    = (const float*)d_in[13];
  const float* dbhh    = (const float*)d_in[14];
  const float* W1      = (const float*)d_in[15];
  const float* l2W     = (const float*)d_in[16];
  const float* l2b     = (const float*)d_in[17];
  const float* l3W     = (const float*)d_in[18];
  const float* l3b     = (const float*)d_in[19];
  const float* Vatt    = (const float*)d_in[20];
  const float* outb    = (const float*)d_in[21];
  const int* inp       = (const int*)d_in[22];
  float* d_out = (float*)d_out_v;

  float* ws = (float*)d_ws;
  size_t off = 0;
  auto take = [&](size_t n) { float* p = ws + off; off += (n + 3) & ~(size_t)3; return p; };
  float* embT   = take((size_t)300 * 32000);
  float* encout = take((size_t)8192 * 512);
  float* w1e    = take((size_t)8192 * 300);
  float* W1T    = take((size_t)300 * 512);
  float* hcat   = take((size_t)128 * 512);
  float* dech   = take((size_t)2 * 2 * 64 * 300);
  float* h1T    = take((size_t)300 * 64);
  float* xdec   = take((size_t)64 * 300);
  float* hbuf   = take((size_t)2 * 2 * 64 * 256);
  unsigned long long* bests = (unsigned long long*)take((size_t)250 * 64 * 2);
  int* flags_enc = (int*)take((size_t)2 * 16 * 16 * 32);  // [layer][group][wg][32]
  int* flags_dec = (int*)take((size_t)76 * 32);

  // encoder scratch in d_out (dead before decoder writes)
  float* emb  = d_out;
  float* gi0f = emb + 2457600;
  float* gi0b = gi0f + 6291456;
  float* x1   = gi0b + 6291456;
  float* gi1f = x1 + 4194304;
  float* gi1b = gi1f + 6291456;

  hipMemsetAsync(flags_enc, 0, (2 * 16 * 16 * 32 + 76 * 32) * sizeof(int), stream);

  k_embed<<<2400, 256, 0, stream>>>((const float4*)emb_enc, inp, (float4*)emb);
  k_transpose<<<dim3(10, 16), 256, 0, stream>>>(W1, W1T, 512, 300);
  k_transpose<<<dim3(10, 1000), 256, 0, stream>>>(emb_dec, embT, 32000, 300);

  // encoder layer 0
  k_gemm128<<<dim3(64, 6), 256, 0, stream>>>(emb, eWih0, ebih0, gi0f, 8192, 768, 300);
  k_gemm128<<<dim3(64, 6), 256, 0, stream>>>(emb, eWih0 + 230400, ebih0 + 768, gi0b, 8192, 768, 300);
  hipMemsetAsync(hbuf, 0, 2 * 2 * 64 * 256 * sizeof(float), stream);
  k_enc_layer<<<dim3(16, 8, 2), 256, 0, stream>>>(gi0f, gi0b, eWhh0, ebhh0, x1, hbuf, flags_enc);

  // encoder layer 1
  k_gemm128<<<dim3(64, 6), 256, 0, stream>>>(x1, eWih1, ebih1, gi1f, 8192, 768, 512);
  k_gemm128<<<dim3(64, 6), 256, 0, stream>>>(x1, eWih1 + 393216, ebih1 + 768, gi1b, 8192, 768, 512);
  hipMemsetAsync(hbuf, 0, 2 * 2 * 64 * 256 * sizeof(float), stream);
  k_enc_layer<<<dim3(16, 8, 2), 256, 0, stream>>>(gi1f, gi1b, eWhh1, ebhh1, encout, hbuf,
                                                  flags_enc + 8192);

  // encoder epilogue
  k_hcat<<<256, 256, 0, stream>>>(x1, encout, hcat);
  k_gemm128<<<dim3(1, 3), 256, 0, stream>>>(hcat, Wout, nullptr, dech, 128, 300, 512);
  k_gemm128<<<dim3(64, 3), 256, 0, stream>>>(encout, W1T, nullptr, w1e, 8192, 300, 512);

  // decoder
  for (int t = 0; t < 32; ++t) {
    int cur = t & 1, nxt = cur ^ 1;
    float* hc = dech + cur * 38400;
    float* hn = dech + nxt * 38400;
    k_dec_step<<<76, 256, 0, stream>>>(hc, hn, h1T, w1e, encout, l2W, l2b, l3W, l3b,
                                       Vatt, emb_dec, dWih, dWhh, dbih, dbhh,
                                       t ? bests : nullptr, xdec, flags_dec, t);
    k_dec_out<<<250, 256, 0, stream>>>(embT, h1T, outb,
                                       d_out + (size_t)t * 2048000, bests);
  }
}

// Round 4
// 11644.631 us; speedup vs baseline: 1.1016x; 1.1016x over previous
//
#include <hip/hip_runtime.h>
#include <math.h>

// Seq2SeqRNN fp32.
// Encoder recurrence: persistent kernel per layer, 256 WGs (16c x 8bgrp x 2dir),
// FENCE-FREE inter-WG protocol: h written via relaxed atomic-exchange (performed
// at the device coherence point), read via relaxed agent atomic-loads (cache-
// bypassing), group flag via relaxed fetch_add; ordering = s_waitcnt vmcnt(0).
// No acquire/release anywhere inside kernels (agent fences cost 10s of us on
// multi-XCD CDNA4: release=L2 writeback, acquire=L2 invalidate).
// Decoder: unfused 4 kernels/step (no in-kernel cross-WG sync).

#define DINL static __device__ __forceinline__

DINL float sigm(float x) { return 1.0f / (1.0f + expf(-x)); }
DINL float dot4f(float4 a, float4 b) { return a.x*b.x + a.y*b.y + a.z*b.z + a.w*b.w; }

DINL unsigned long long packmax(float x, int v) {
  unsigned u = __float_as_uint(x);
  u = (u & 0x80000000u) ? ~u : (u | 0x80000000u);
  return ((unsigned long long)u << 32) | (unsigned)(~v);  // ties -> smaller v wins
}
DINL unsigned long long umax64(unsigned long long a, unsigned long long b) {
  return a > b ? a : b;
}

// ---------------- embedding gather (300 = 75 float4)
__global__ __launch_bounds__(256) void k_embed(const float4* __restrict__ E,
                                               const int* __restrict__ inp,
                                               float4* __restrict__ out) {
  int i = blockIdx.x * 256 + threadIdx.x;
  if (i >= 8192 * 75) return;
  int row = i / 75, q = i - row * 75;
  out[i] = E[(size_t)inp[row] * 75 + q];
}

// ---------------- transpose B[c*R+r] = A[r*C+c]
__global__ __launch_bounds__(256) void k_transpose(const float* __restrict__ A,
                                                   float* __restrict__ B, int R, int C) {
  __shared__ float tile[32][33];
  int c0 = blockIdx.x * 32, r0 = blockIdx.y * 32;
  int tx = threadIdx.x & 31, ty = threadIdx.x >> 5;
  for (int i = 0; i < 32; i += 8) {
    int r = r0 + ty + i, c = c0 + tx;
    if (r < R && c < C) tile[ty + i][tx] = A[(size_t)r * C + c];
  }
  __syncthreads();
  for (int i = 0; i < 32; i += 8) {
    int c = c0 + ty + i, r = r0 + tx;
    if (c < C && r < R) B[(size_t)c * R + r] = tile[tx][ty + i];
  }
}

// ---------------- fp32 GEMM-NT: C[n,m] = sum_k A[n,k]*B[m,k] + bias[m]
__global__ __launch_bounds__(256) void k_gemm128(const float* __restrict__ A,
                                                 const float* __restrict__ B,
                                                 const float* __restrict__ bias,
                                                 float* __restrict__ C,
                                                 int N, int M, int K) {
  __shared__ float As[8][132];
  __shared__ float Bs[8][132];
  const int tid = threadIdx.x;
  const int bn = blockIdx.x * 128, bm = blockIdx.y * 128;
  const int tn = (tid >> 4) << 3, tm = (tid & 15) << 3;
  const int r = tid & 127;
  const bool isB = tid >= 128;
  const float* src = isB ? (B + (size_t)(bm + r) * K) : (A + (size_t)(bn + r) * K);
  const bool rowok = isB ? (bm + r < M) : (bn + r < N);
  float acc[8][8] = {};
  for (int k0 = 0; k0 < K; k0 += 8) {
    float v[8];
    if (rowok && k0 + 8 <= K) {
      float4 p0 = *(const float4*)(src + k0);
      float4 p1 = *(const float4*)(src + k0 + 4);
      v[0]=p0.x; v[1]=p0.y; v[2]=p0.z; v[3]=p0.w;
      v[4]=p1.x; v[5]=p1.y; v[6]=p1.z; v[7]=p1.w;
    } else {
#pragma unroll
      for (int j = 0; j < 8; ++j) v[j] = (rowok && k0 + j < K) ? src[k0 + j] : 0.0f;
    }
    float (*dst)[132] = isB ? Bs : As;
#pragma unroll
    for (int j = 0; j < 8; ++j) dst[j][r] = v[j];
    __syncthreads();
#pragma unroll
    for (int kk = 0; kk < 8; ++kk) {
      float a[8], b[8];
      *(float4*)&a[0] = *(const float4*)&As[kk][tn];
      *(float4*)&a[4] = *(const float4*)&As[kk][tn + 4];
      *(float4*)&b[0] = *(const float4*)&Bs[kk][tm];
      *(float4*)&b[4] = *(const float4*)&Bs[kk][tm + 4];
#pragma unroll
      for (int i = 0; i < 8; ++i)
#pragma unroll
        for (int j = 0; j < 8; ++j) acc[i][j] += a[i] * b[j];
    }
    __syncthreads();
  }
#pragma unroll
  for (int i = 0; i < 8; ++i) {
    int row = bn + tn + i;
    if (row >= N) continue;
#pragma unroll
    for (int j = 0; j < 8; ++j) {
      int col = bm + tm + j;
      if (col < M) C[(size_t)row * M + col] = acc[i][j] + (bias ? bias[col] : 0.0f);
    }
  }
}

// ---------------- persistent encoder layer, fence-free protocol.
// grid (16 cgrp, 8 bgrp, 2 dir) = 256 WGs of 128 (16 cols x 8 batches).
// Sync group = 16 WGs sharing (dir,bgrp); one flag counter per group.
__global__ __launch_bounds__(128) void k_enc_layer(
    const float* __restrict__ giF, const float* __restrict__ giB,
    const float* __restrict__ Whh,   // [2][768][256]
    const float* __restrict__ bhh,   // [2][768]
    float* __restrict__ y,           // [128][64][512]
    float* __restrict__ hbuf,        // [2 pp][2 dir][64][256]
    unsigned* __restrict__ flags) {  // [16 groups][32]
  const int dir = blockIdx.z;
  const int c0 = blockIdx.x << 4;
  const int b0 = blockIdx.y << 3;
  const int tid = threadIdx.x;
  const int cl = tid & 15, bl = tid >> 4;  // round-2 mapping (0 bank conflicts)
  const float* gi = dir ? giB : giF;
  const float* W = Whh + (size_t)dir * 196608;
  const float* bh = bhh + dir * 768;
  float* hb = hbuf + dir * 16384;
  unsigned* flag = flags + ((dir << 3) + blockIdx.y) * 32;

  __shared__ __align__(16) float W0[16][260], W1[16][260], W2[16][260];
  __shared__ __align__(16) float hsh[8][260];

  for (int i = tid; i < 48 * 64; i += 128) {
    int row = i >> 6, q = i & 63;
    int g = row >> 4, rc = row & 15;
    float4 w = ((const float4*)W)[(size_t)(c0 + rc + (g << 8)) * 64 + q];
    float* dst = (g == 0) ? &W0[rc][0] : ((g == 1) ? &W1[rc][0] : &W2[rc][0]);
    *(float4*)&dst[q << 2] = w;
  }
  __syncthreads();

  const int b = b0 + bl, c = c0 + cl;
  const float bhr = bh[c], bhz = bh[256 + c], bhn = bh[512 + c];

  // gi(t=0) prefetch
  float gr, gz, gn;
  {
    const int tt0 = dir ? 127 : 0;
    const float* gp = gi + (size_t)tt0 * 49152 + (size_t)b * 768;
    gr = gp[c]; gz = gp[256 + c]; gn = gp[512 + c];
  }

  for (int t = 0; t < 128; ++t) {
    if (t) {
      if (tid == 0) {
        while (__hip_atomic_fetch_add(flag, 0u, __ATOMIC_RELAXED,
                                      __HIP_MEMORY_SCOPE_AGENT) < 16u * (unsigned)t)
          __builtin_amdgcn_s_sleep(2);
      }
      __syncthreads();
    }
    const int pp = t & 1;
    // stage this group's 8 h rows (2048 floats) via cache-bypassing atomic loads
    {
      const unsigned* hsrc = (const unsigned*)(hb + pp * 32768 + (b0 << 8));
      for (int i = tid; i < 2048; i += 128) {
        unsigned ub = __hip_atomic_load(hsrc + i, __ATOMIC_RELAXED,
                                        __HIP_MEMORY_SCOPE_AGENT);
        hsh[i >> 8][i & 255] = __uint_as_float(ub);
      }
    }
    __syncthreads();

    // prefetch next gi
    float nr = 0.f, nz = 0.f, nn = 0.f;
    if (t < 127) {
      const int tn_ = dir ? 126 - t : t + 1;
      const float* gp2 = gi + (size_t)tn_ * 49152 + (size_t)b * 768;
      nr = gp2[c]; nz = gp2[256 + c]; nn = gp2[512 + c];
    }

    float ar = 0.f, az = 0.f, an = 0.f;
#pragma unroll 8
    for (int kq = 0; kq < 64; ++kq) {
      const int k = kq << 2;
      float4 hv = *(const float4*)&hsh[bl][k];
      ar += dot4f(hv, *(const float4*)&W0[cl][k]);
      az += dot4f(hv, *(const float4*)&W1[cl][k]);
      an += dot4f(hv, *(const float4*)&W2[cl][k]);
    }

    float rg = sigm(gr + ar + bhr);
    float zg = sigm(gz + az + bhz);
    float ng = tanhf(gn + rg * (an + bhn));
    float hnew = (1.f - zg) * ng + zg * hsh[bl][c];

    const int tt = dir ? 127 - t : t;
    // coherent write-through of new h (RMW is performed at the coherence point)
    __hip_atomic_exchange((unsigned*)&hb[(pp ^ 1) * 32768 + (b << 8) + c],
                          __float_as_uint(hnew), __ATOMIC_RELAXED,
                          __HIP_MEMORY_SCOPE_AGENT);
    y[(size_t)tt * 32768 + (b << 9) + (dir << 8) + c] = hnew;

    asm volatile("s_waitcnt vmcnt(0)" ::: "memory");
    __syncthreads();
    if (t < 127 && tid == 0)
      __hip_atomic_fetch_add(flag, 1u, __ATOMIC_RELAXED, __HIP_MEMORY_SCOPE_AGENT);

    gr = nr; gz = nz; gn = nn;
  }
}

// ---------------- hcat[2][64][512]
__global__ __launch_bounds__(256) void k_hcat(const float* __restrict__ x1,
                                              const float* __restrict__ encout,
                                              float* __restrict__ hcat) {
  int i = blockIdx.x * 256 + threadIdx.x;  // 65536
  int l = i >> 15, r = i & 32767, b = r >> 9, d = r & 511;
  const float* src = l ? encout : x1;
  int ts = (d < 256) ? 127 : 0;
  hcat[i] = src[((size_t)(ts << 6) + b) * 512 + d];
}

// ---------------- decoder attention block: one WG per batch b.
__global__ __launch_bounds__(256) void k_dec_att(
    const float* __restrict__ h1, const float* __restrict__ w1e,
    const float* __restrict__ encout,
    const float* __restrict__ l2W, const float* __restrict__ l2b,
    const float* __restrict__ l3W, const float* __restrict__ l3b,
    const float* __restrict__ Vatt, const float* __restrict__ embdec,
    const unsigned long long* __restrict__ prev,  // [250][64] or null (step 0)
    float* __restrict__ xdec) {
  const int b = blockIdx.x, tid = threadIdx.x;
  __shared__ __align__(16) float h1s[304];
  __shared__ __align__(16) float w2h[304];
  __shared__ __align__(16) float eXa[816];
  __shared__ float aa[128];
  __shared__ float red[128];
  __shared__ unsigned long long redb[128];

  if (tid < 128) {
    unsigned long long m = 0ULL;
    if (prev) {
      m = prev[(size_t)tid * 64 + b];
      if (tid < 122) m = umax64(m, prev[(size_t)(tid + 128) * 64 + b]);
    }
    redb[tid] = m;
  }
  for (int i = tid; i < 300; i += 256) h1s[i] = h1[b * 300 + i];
  __syncthreads();
  for (int s = 64; s > 0; s >>= 1) {
    if (tid < s) redb[tid] = umax64(redb[tid], redb[tid + s]);
    __syncthreads();
  }
  const int ib = prev ? (int)(~(unsigned)(redb[0] & 0xFFFFFFFFULL)) : 0;

  for (int m = tid; m < 300; m += 256) {
    const float4* wr = (const float4*)(l2W + (size_t)m * 300);
    const float4* hr = (const float4*)h1s;
    float acc = l2b[m];
    for (int q = 0; q < 75; ++q) acc += dot4f(wr[q], hr[q]);
    w2h[m] = acc;
  }
  __syncthreads();

  if (tid < 128) {
    const float4* wp = (const float4*)(w1e + ((size_t)(tid << 6) + b) * 300);
    const float4* vp = (const float4*)Vatt;
    const float4* hp = (const float4*)w2h;
    float acc = 0.f;
    for (int q = 0; q < 75; ++q) {
      float4 w = wp[q], h = hp[q], v = vp[q];
      acc += tanhf(w.x + h.x) * v.x + tanhf(w.y + h.y) * v.y +
             tanhf(w.z + h.z) * v.z + tanhf(w.w + h.w) * v.w;
    }
    aa[tid] = acc;
    red[tid] = acc;
  }
  __syncthreads();
  for (int s = 64; s > 0; s >>= 1) {
    if (tid < s) red[tid] = fmaxf(red[tid], red[tid + s]);
    __syncthreads();
  }
  float mx = red[0];
  __syncthreads();
  if (tid < 128) {
    float ex = expf(aa[tid] - mx);
    aa[tid] = ex;
    red[tid] = ex;
  }
  __syncthreads();
  for (int s = 64; s > 0; s >>= 1) {
    if (tid < s) red[tid] += red[tid + s];
    __syncthreads();
  }
  float inv = 1.0f / red[0];
  __syncthreads();
  if (tid < 128) aa[tid] *= inv;
  for (int d = tid; d < 300; d += 256) eXa[d] = embdec[(size_t)ib * 300 + d];
  __syncthreads();

  for (int d = tid; d < 512; d += 256) {
    float acc = 0.f;
    for (int s = 0; s < 128; ++s) acc += aa[s] * encout[((size_t)(s << 6) + b) * 512 + d];
    eXa[300 + d] = acc;
  }
  __syncthreads();

  for (int m = tid; m < 300; m += 256) {
    const float4* wr = (const float4*)(l3W + (size_t)m * 812);
    const float4* xr = (const float4*)eXa;
    float acc = l3b[m];
    for (int q = 0; q < 203; ++q) acc += dot4f(wr[q], xr[q]);
    xdec[b * 300 + m] = acc;
  }
}

// ---------------- decoder GRU cell (300/300). block 256 = 16c x 16b, grid (19,4).
__global__ __launch_bounds__(256) void k_gru300(
    const float* __restrict__ xin, const float* __restrict__ hin,
    float* __restrict__ hout, float* __restrict__ houtT,
    const float* __restrict__ Wih, const float* __restrict__ Whh,
    const float* __restrict__ bih, const float* __restrict__ bhh) {
  const int tid = threadIdx.x;
  const int cl = tid & 15, bl = tid >> 4;
  const int c = blockIdx.x * 16 + cl;
  const int b0 = blockIdx.y * 16;
  const int b = b0 + bl;
  __shared__ __align__(16) float xs[16][300];
  __shared__ __align__(16) float hs[16][300];
  for (int i = tid; i < 16 * 75; i += 256) {
    int row = i / 75, q = i - row * 75;
    ((float4*)&xs[row][0])[q] = ((const float4*)(xin + (size_t)(b0 + row) * 300))[q];
    ((float4*)&hs[row][0])[q] = ((const float4*)(hin + (size_t)(b0 + row) * 300))[q];
  }
  __syncthreads();
  if (c < 300) {
    float gir = bih[c], giz = bih[300 + c], gin = bih[600 + c];
    float ghr = bhh[c], ghz = bhh[300 + c], ghn = bhh[600 + c];
    const float4* wir = (const float4*)(Wih + (size_t)c * 300);
    const float4* wiz = (const float4*)(Wih + (size_t)(300 + c) * 300);
    const float4* win = (const float4*)(Wih + (size_t)(600 + c) * 300);
    const float4* whr = (const float4*)(Whh + (size_t)c * 300);
    const float4* whz = (const float4*)(Whh + (size_t)(300 + c) * 300);
    const float4* whn = (const float4*)(Whh + (size_t)(600 + c) * 300);
    const float4* xr = (const float4*)&xs[bl][0];
    const float4* hr = (const float4*)&hs[bl][0];
    for (int q = 0; q < 75; ++q) {
      float4 xv = xr[q], hv = hr[q];
      gir += dot4f(xv, wir[q]);
      giz += dot4f(xv, wiz[q]);
      gin += dot4f(xv, win[q]);
      ghr += dot4f(hv, whr[q]);
      ghz += dot4f(hv, whz[q]);
      ghn += dot4f(hv, whn[q]);
    }
    float r = sigm(gir + ghr), z = sigm(giz + ghz);
    float n = tanhf(gin + r * ghn);
    float hnew = (1.f - z) * n + z * hs[bl][c];
    hout[(size_t)b * 300 + c] = hnew;
    if (houtT) houtT[(size_t)c * 64 + b] = hnew;
  }
}

// ---------------- logits + fused argmax partials. grid 250; block = 128 v x 2 khalf.
__global__ __launch_bounds__(256) void k_dec_out(const float* __restrict__ embT,
                                                 const float* __restrict__ h1T,
                                                 const float* __restrict__ outb,
                                                 float* __restrict__ out,
                                                 unsigned long long* __restrict__ bests) {
  const int tid = threadIdx.x;
  const int vt = tid & 127, kh = tid >> 7;
  const int v = blockIdx.x * 128 + vt;
  __shared__ float sacc[128][65];
  float acc[64];
#pragma unroll
  for (int i = 0; i < 64; ++i) acc[i] = 0.f;
  const int kb = kh * 150;
  for (int k = kb; k < kb + 150; ++k) {
    float ev = embT[(size_t)k * 32000 + v];
    const float* h = h1T + k * 64;
#pragma unroll
    for (int i = 0; i < 64; ++i) acc[i] += ev * h[i];
  }
  if (kh) {
#pragma unroll
    for (int i = 0; i < 64; ++i) sacc[vt][i] = acc[i];
  }
  __syncthreads();
  if (!kh) {
    float bo = outb[v];
#pragma unroll
    for (int i = 0; i < 64; ++i) {
      float val = acc[i] + sacc[vt][i] + bo;
      out[(size_t)i * 32000 + v] = val;
      sacc[vt][i] = val;
    }
  }
  __syncthreads();
  if (tid < 64) {
    unsigned long long best = 0ULL;
    const int v0 = blockIdx.x * 128;
    for (int q = 0; q < 128; ++q)
      best = umax64(best, packmax(sacc[q][tid], v0 + q));
    bests[(size_t)blockIdx.x * 64 + tid] = best;
  }
}

extern "C" void kernel_launch(void* const* d_in, const int* in_sizes, int n_in,
                              void* d_out_v, int out_size, void* d_ws, size_t ws_size,
                              hipStream_t stream) {
  (void)in_sizes; (void)n_in; (void)out_size; (void)ws_size;
  const float* emb_enc = (const float*)d_in[0];
  const float* eWih0   = (const float*)d_in[1];
  const float* eWhh0   = (const float*)d_in[2];
  const float* ebih0   = (const float*)d_in[3];
  const float* ebhh0   = (const float*)d_in[4];
  const float* eWih1   = (const float*)d_in[5];
  const float* eWhh1   = (const float*)d_in[6];
  const float* ebih1   = (const float*)d_in[7];
  const float* ebhh1   = (const float*)d_in[8];
  const float* Wout    = (const float*)d_in[9];
  const float* emb_dec = (const float*)d_in[10];
  const float* dWih    = (const float*)d_in[11];
  const float* dWhh    = (const float*)d_in[12];
  const float* dbih    = (const float*)d_in[13];
  const float* dbhh    = (const float*)d_in[14];
  const float* W1      = (const float*)d_in[15];
  const float* l2W     = (const float*)d_in[16];
  const float* l2b     = (const float*)d_in[17];
  const float* l3W     = (const float*)d_in[18];
  const float* l3b     = (const float*)d_in[19];
  const float* Vatt    = (const float*)d_in[20];
  const float* outb    = (const float*)d_in[21];
  const int* inp       = (const int*)d_in[22];
  float* d_out = (float*)d_out_v;

  float* ws = (float*)d_ws;
  size_t off = 0;
  auto take = [&](size_t n) { float* p = ws + off; off += (n + 3) & ~(size_t)3; return p; };
  float* embT   = take((size_t)300 * 32000);
  float* encout = take((size_t)8192 * 512);
  float* w1e    = take((size_t)8192 * 300);
  float* W1T    = take((size_t)300 * 512);
  float* hcat   = take((size_t)128 * 512);
  float* dech   = take((size_t)2 * 2 * 64 * 300);
  float* h1T    = take((size_t)300 * 64);
  float* xdec   = take((size_t)64 * 300);
  float* hbuf   = take((size_t)2 * 2 * 64 * 256);
  unsigned long long* bests = (unsigned long long*)take((size_t)250 * 64 * 2);
  unsigned* flags = (unsigned*)take((size_t)2 * 16 * 32);  // [layer][group][32]

  // encoder scratch in d_out (dead before decoder writes)
  float* emb  = d_out;
  float* gi0f = emb + 2457600;
  float* gi0b = gi0f + 6291456;
  float* x1   = gi0b + 6291456;
  float* gi1f = x1 + 4194304;
  float* gi1b = gi1f + 6291456;

  hipMemsetAsync(flags, 0, 2 * 16 * 32 * sizeof(unsigned), stream);

  k_embed<<<2400, 256, 0, stream>>>((const float4*)emb_enc, inp, (float4*)emb);
  k_transpose<<<dim3(10, 16), 256, 0, stream>>>(W1, W1T, 512, 300);
  k_transpose<<<dim3(10, 1000), 256, 0, stream>>>(emb_dec, embT, 32000, 300);

  // encoder layer 0
  k_gemm128<<<dim3(64, 6), 256, 0, stream>>>(emb, eWih0, ebih0, gi0f, 8192, 768, 300);
  k_gemm128<<<dim3(64, 6), 256, 0, stream>>>(emb, eWih0 + 230400, ebih0 + 768, gi0b, 8192, 768, 300);
  hipMemsetAsync(hbuf, 0, 2 * 2 * 64 * 256 * sizeof(float), stream);
  k_enc_layer<<<dim3(16, 8, 2), 128, 0, stream>>>(gi0f, gi0b, eWhh0, ebhh0, x1, hbuf, flags);

  // encoder layer 1
  k_gemm128<<<dim3(64, 6), 256, 0, stream>>>(x1, eWih1, ebih1, gi1f, 8192, 768, 512);
  k_gemm128<<<dim3(64, 6), 256, 0, stream>>>(x1, eWih1 + 393216, ebih1 + 768, gi1b, 8192, 768, 512);
  hipMemsetAsync(hbuf, 0, 2 * 2 * 64 * 256 * sizeof(float), stream);
  k_enc_layer<<<dim3(16, 8, 2), 128, 0, stream>>>(gi1f, gi1b, eWhh1, ebhh1, encout, hbuf,
                                                  flags + 512);

  // encoder epilogue
  k_hcat<<<256, 256, 0, stream>>>(x1, encout, hcat);
  k_gemm128<<<dim3(1, 3), 256, 0, stream>>>(hcat, Wout, nullptr, dech, 128, 300, 512);
  k_gemm128<<<dim3(64, 3), 256, 0, stream>>>(encout, W1T, nullptr, w1e, 8192, 300, 512);

  // decoder
  for (int t = 0; t < 32; ++t) {
    int cur = t & 1, nxt = cur ^ 1;
    float* hc = dech + cur * 38400;
    float* hn = dech + nxt * 38400;
    k_dec_att<<<64, 256, 0, stream>>>(hc + 19200, w1e, encout, l2W, l2b, l3W, l3b,
                                      Vatt, emb_dec, t ? bests : nullptr, xdec);
    k_gru300<<<dim3(19, 4), 256, 0, stream>>>(xdec, hc, hn, nullptr,
                                              dWih, dWhh, dbih, dbhh);
    k_gru300<<<dim3(19, 4), 256, 0, stream>>>(hn, hc + 19200, hn + 19200, h1T,
                                              dWih + 270000, dWhh + 270000,
                                              dbih + 900, dbhh + 900);
    k_dec_out<<<250, 256, 0, stream>>>(embT, h1T, outb,
                                       d_out + (size_t)t * 2048000, bests);
  }
}

// Round 6
// 11027.400 us; speedup vs baseline: 1.1633x; 1.0560x over previous
//
#include <hip/hip_runtime.h>
#include <math.h>

// Seq2SeqRNN fp32.
// Encoder recurrence: SYNC-FREE persistent WGs (2 batches x 1 dir each, h in LDS,
// Whh streamed from L2 in packed k-pair layout, v_pk_fma_f32 via float2 ext-vector).
// Decoder: ONE persistent kernel for all 32 steps, 256 WGs, phases separated by
// fence-free barriers (relaxed exchange + bypass atomic loads + s_waitcnt vmcnt(0)).
// No acquire/release anywhere (agent fences = L2 writeback/invalidate, 10s of us).
// r6 fix: k_enc_rec per-dir W2 stride is 196608 floats (was 393216 = whole buffer,
// so both layers' backward GRUs read the wrong/unpacked weights).

typedef unsigned long long ull;
typedef float v2f __attribute__((ext_vector_type(2)));

#define DINL static __device__ __forceinline__

DINL float sigm(float x) { return 1.0f / (1.0f + expf(-x)); }
DINL float dot4f(float4 a, float4 b) { return a.x*b.x + a.y*b.y + a.z*b.z + a.w*b.w; }

DINL ull packmax(float x, int v) {
  unsigned u = __float_as_uint(x);
  u = (u & 0x80000000u) ? ~u : (u | 0x80000000u);
  return ((ull)u << 32) | (unsigned)(~v);  // ties -> smaller v wins
}
DINL ull umax64(ull a, ull b) { return a > b ? a : b; }

// cache-bypassing load / write-through store (relaxed, agent scope) — proven r4
DINL float atl(const float* p) {
  unsigned u = __hip_atomic_load((const unsigned*)p, __ATOMIC_RELAXED,
                                 __HIP_MEMORY_SCOPE_AGENT);
  return __uint_as_float(u);
}
DINL void atsf(float* p, float v) {
  __hip_atomic_exchange((unsigned*)p, __float_as_uint(v), __ATOMIC_RELAXED,
                        __HIP_MEMORY_SCOPE_AGENT);
}
DINL ull atl64(const ull* p) {
  return __hip_atomic_load(p, __ATOMIC_RELAXED, __HIP_MEMORY_SCOPE_AGENT);
}
DINL void ats64(ull* p, ull v) {
  __hip_atomic_exchange(p, v, __ATOMIC_RELAXED, __HIP_MEMORY_SCOPE_AGENT);
}

// grid-wide fence-free barrier: grid must be exactly 256 WGs of 256 threads.
DINL void gbar(unsigned* flags, int wg, unsigned target, int tid) {
  asm volatile("s_waitcnt vmcnt(0)" ::: "memory");
  __syncthreads();
  if (tid == 0)
    __hip_atomic_exchange(&flags[wg * 32], target, __ATOMIC_RELAXED,
                          __HIP_MEMORY_SCOPE_AGENT);
  while (__hip_atomic_load(&flags[tid * 32], __ATOMIC_RELAXED,
                           __HIP_MEMORY_SCOPE_AGENT) < target)
    __builtin_amdgcn_s_sleep(1);
  __syncthreads();
}

// ---------------- embedding gather (300 = 75 float4)
__global__ __launch_bounds__(256) void k_embed(const float4* __restrict__ E,
                                               const int* __restrict__ inp,
                                               float4* __restrict__ out) {
  int i = blockIdx.x * 256 + threadIdx.x;
  if (i >= 8192 * 75) return;
  int row = i / 75, q = i - row * 75;
  out[i] = E[(size_t)inp[row] * 75 + q];
}

// ---------------- transpose B[c*R+r] = A[r*C+c]
__global__ __launch_bounds__(256) void k_transpose(const float* __restrict__ A,
                                                   float* __restrict__ B, int R, int C) {
  __shared__ float tile[32][33];
  int c0 = blockIdx.x * 32, r0 = blockIdx.y * 32;
  int tx = threadIdx.x & 31, ty = threadIdx.x >> 5;
  for (int i = 0; i < 32; i += 8) {
    int r = r0 + ty + i, c = c0 + tx;
    if (r < R && c < C) tile[ty + i][tx] = A[(size_t)r * C + c];
  }
  __syncthreads();
  for (int i = 0; i < 32; i += 8) {
    int c = c0 + ty + i, r = r0 + tx;
    if (c < C && r < R) B[(size_t)c * R + r] = tile[tx][ty + i];
  }
}

// ---------------- pack Whh[2][768][256] -> W2[2][128 kp][768 gc][2]
__global__ __launch_bounds__(256) void k_packW(const float* __restrict__ Whh,
                                               float* __restrict__ W2) {
  int i = blockIdx.x * 256 + threadIdx.x;  // 2*128*768
  if (i >= 196608) return;
  int d = i / 98304, r = i - d * 98304, kp = r / 768, gc = r - kp * 768;
  const float* src = Whh + (size_t)d * 196608 + (size_t)gc * 256 + kp * 2;
  float* dst = W2 + (size_t)i * 2;
  dst[0] = src[0];
  dst[1] = src[1];
}

// ---------------- fp32 GEMM-NT: C[n,m] = sum_k A[n,k]*B[m,k] + bias[m]
__global__ __launch_bounds__(256) void k_gemm128(const float* __restrict__ A,
                                                 const float* __restrict__ B,
                                                 const float* __restrict__ bias,
                                                 float* __restrict__ C,
                                                 int N, int M, int K) {
  __shared__ float As[8][132];
  __shared__ float Bs[8][132];
  const int tid = threadIdx.x;
  const int bn = blockIdx.x * 128, bm = blockIdx.y * 128;
  const int tn = (tid >> 4) << 3, tm = (tid & 15) << 3;
  const int r = tid & 127;
  const bool isB = tid >= 128;
  const float* src = isB ? (B + (size_t)(bm + r) * K) : (A + (size_t)(bn + r) * K);
  const bool rowok = isB ? (bm + r < M) : (bn + r < N);
  float acc[8][8] = {};
  for (int k0 = 0; k0 < K; k0 += 8) {
    float v[8];
    if (rowok && k0 + 8 <= K) {
      float4 p0 = *(const float4*)(src + k0);
      float4 p1 = *(const float4*)(src + k0 + 4);
      v[0]=p0.x; v[1]=p0.y; v[2]=p0.z; v[3]=p0.w;
      v[4]=p1.x; v[5]=p1.y; v[6]=p1.z; v[7]=p1.w;
    } else {
#pragma unroll
      for (int j = 0; j < 8; ++j) v[j] = (rowok && k0 + j < K) ? src[k0 + j] : 0.0f;
    }
    float (*dst)[132] = isB ? Bs : As;
#pragma unroll
    for (int j = 0; j < 8; ++j) dst[j][r] = v[j];
    __syncthreads();
#pragma unroll
    for (int kk = 0; kk < 8; ++kk) {
      float a[8], b[8];
      *(float4*)&a[0] = *(const float4*)&As[kk][tn];
      *(float4*)&a[4] = *(const float4*)&As[kk][tn + 4];
      *(float4*)&b[0] = *(const float4*)&Bs[kk][tm];
      *(float4*)&b[4] = *(const float4*)&Bs[kk][tm + 4];
#pragma unroll
      for (int i = 0; i < 8; ++i)
#pragma unroll
        for (int j = 0; j < 8; ++j) acc[i][j] += a[i] * b[j];
    }
    __syncthreads();
  }
#pragma unroll
  for (int i = 0; i < 8; ++i) {
    int row = bn + tn + i;
    if (row >= N) continue;
#pragma unroll
    for (int j = 0; j < 8; ++j) {
      int col = bm + tm + j;
      if (col < M) C[(size_t)row * M + col] = acc[i][j] + (bias ? bias[col] : 0.0f);
    }
  }
}

// ---------------- sync-free encoder recurrence.
// grid (32 bgrp, 2 dir), 256 threads; WG owns 2 batches, computes all 768 gates.
// h ping-pong in LDS; Whh streamed from L2 (packed); zero inter-WG traffic.
__global__ __launch_bounds__(256) void k_enc_rec(
    const float* __restrict__ giF, const float* __restrict__ giB,
    const float* __restrict__ W2,    // [2][128][768][2] floats
    const float* __restrict__ bhh,   // [2][768]
    float* __restrict__ y) {         // [128][64][512]
  const int b0 = blockIdx.x * 2;
  const int dir = blockIdx.y;
  const int c = threadIdx.x;
  const float* gi = dir ? giB : giF;
  const v2f* Wv = (const v2f*)(W2 + (size_t)dir * 196608);  // r6 FIX (was 393216)
  const float* bh = bhh + dir * 768;

  __shared__ __align__(16) float hls[2][2][258];
  for (int i = c; i < 2 * 2 * 258; i += 256) ((float*)hls)[i] = 0.0f;
  __syncthreads();

  const float bhr = bh[c], bhz = bh[256 + c], bhn = bh[512 + c];

  const int tt0 = dir ? 127 : 0;
  const float* g0p = gi + (size_t)tt0 * 49152 + (size_t)b0 * 768;
  float g0r = g0p[c], g0z = g0p[256 + c], g0n = g0p[512 + c];
  float g1r = g0p[768 + c], g1z = g0p[1024 + c], g1n = g0p[1280 + c];

  for (int t = 0; t < 128; ++t) {
    const int cu = t & 1;
    float p0r = 0, p0z = 0, p0n = 0, p1r = 0, p1z = 0, p1n = 0;
    if (t < 127) {  // prefetch next gi under the FMA loop
      const int tn_ = dir ? 126 - t : t + 1;
      const float* gp = gi + (size_t)tn_ * 49152 + (size_t)b0 * 768;
      p0r = gp[c]; p0z = gp[256 + c]; p0n = gp[512 + c];
      p1r = gp[768 + c]; p1z = gp[1024 + c]; p1n = gp[1280 + c];
    }
    v2f a0r = {0,0}, a0z = {0,0}, a0n = {0,0};
    v2f a1r = {0,0}, a1z = {0,0}, a1n = {0,0};
    const float* h0p = &hls[cu][0][0];
    const float* h1p = &hls[cu][1][0];
#pragma unroll 4
    for (int kp = 0; kp < 128; ++kp) {
      v2f wr = Wv[kp * 768 + c];
      v2f wz = Wv[kp * 768 + 256 + c];
      v2f wn = Wv[kp * 768 + 512 + c];
      v2f h0 = *(const v2f*)&h0p[kp * 2];
      v2f h1 = *(const v2f*)&h1p[kp * 2];
      a0r += h0 * wr; a0z += h0 * wz; a0n += h0 * wn;
      a1r += h1 * wr; a1z += h1 * wz; a1n += h1 * wn;
    }
    float r0 = sigm(g0r + a0r.x + a0r.y + bhr);
    float z0 = sigm(g0z + a0z.x + a0z.y + bhz);
    float n0 = tanhf(g0n + r0 * (a0n.x + a0n.y + bhn));
    float h0new = (1.f - z0) * n0 + z0 * h0p[c];
    float r1 = sigm(g1r + a1r.x + a1r.y + bhr);
    float z1 = sigm(g1z + a1z.x + a1z.y + bhz);
    float n1 = tanhf(g1n + r1 * (a1n.x + a1n.y + bhn));
    float h1new = (1.f - z1) * n1 + z1 * h1p[c];
    hls[cu ^ 1][0][c] = h0new;
    hls[cu ^ 1][1][c] = h1new;
    const int tw = dir ? 127 - t : t;
    float* yp = y + (size_t)tw * 32768 + (size_t)b0 * 512 + dir * 256 + c;
    yp[0] = h0new;
    yp[512] = h1new;
    g0r = p0r; g0z = p0z; g0n = p0n; g1r = p1r; g1z = p1z; g1n = p1n;
    __syncthreads();
  }
}

// ---------------- hcat[2][64][512]
__global__ __launch_bounds__(256) void k_hcat(const float* __restrict__ x1,
                                              const float* __restrict__ encout,
                                              float* __restrict__ hcat) {
  int i = blockIdx.x * 256 + threadIdx.x;  // 65536
  int l = i >> 15, r = i & 32767, b = r >> 9, d = r & 511;
  const float* src = l ? encout : x1;
  int ts = (d < 256) ? 127 : 0;
  hcat[i] = src[((size_t)(ts << 6) + b) * 512 + d];
}

// ---------------- decoder GRU cell phase (300/300), cb in [0,76); atomic staging
DINL void gru_at(int cb, int tid, const float* __restrict__ xin,
                 const float* __restrict__ hin, float* __restrict__ hout,
                 float* __restrict__ houtT,
                 const float* __restrict__ Wih, const float* __restrict__ Whh,
                 const float* __restrict__ bih, const float* __restrict__ bhh,
                 float* xs, float* hs) {
  const int cchunk = cb % 19, bchunk = cb / 19;
  const int cl = tid & 15, bl = tid >> 4;
  const int c = cchunk * 16 + cl;
  const int b0 = bchunk * 16, bq = b0 + bl;
  for (int i = tid; i < 4800; i += 256) {
    int row = i / 300, q = i - row * 300;
    xs[i] = atl(xin + (size_t)(b0 + row) * 300 + q);
    hs[i] = atl(hin + (size_t)(b0 + row) * 300 + q);
  }
  __syncthreads();
  if (c < 300) {
    float gir = bih[c], giz = bih[300 + c], gin = bih[600 + c];
    float ghr = bhh[c], ghz = bhh[300 + c], ghn = bhh[600 + c];
    const float4* wir = (const float4*)(Wih + (size_t)c * 300);
    const float4* wiz = (const float4*)(Wih + (size_t)(300 + c) * 300);
    const float4* win = (const float4*)(Wih + (size_t)(600 + c) * 300);
    const float4* whr = (const float4*)(Whh + (size_t)c * 300);
    const float4* whz = (const float4*)(Whh + (size_t)(300 + c) * 300);
    const float4* whn = (const float4*)(Whh + (size_t)(600 + c) * 300);
    const float4* xr = (const float4*)(xs + bl * 300);
    const float4* hr = (const float4*)(hs + bl * 300);
    for (int q = 0; q < 75; ++q) {
      float4 xv = xr[q], hv = hr[q];
      gir += dot4f(xv, wir[q]);
      giz += dot4f(xv, wiz[q]);
      gin += dot4f(xv, win[q]);
      ghr += dot4f(hv, whr[q]);
      ghz += dot4f(hv, whz[q]);
      ghn += dot4f(hv, whn[q]);
    }
    float r = sigm(gir + ghr), z = sigm(giz + ghz);
    float n = tanhf(gin + r * ghn);
    float hnew = (1.f - z) * n + z * hs[bl * 300 + c];
    atsf(&hout[(size_t)bq * 300 + c], hnew);
    if (houtT) atsf(&houtT[(size_t)c * 64 + bq], hnew);
  }
}

// ---------------- persistent decoder: all 32 steps. grid 256 x 256 (1 WG/CU).
__global__ __launch_bounds__(256) void k_dec_all(
    float* __restrict__ dech, float* __restrict__ h1T, float* __restrict__ xdec,
    ull* __restrict__ bests, unsigned* __restrict__ flags,
    const float* __restrict__ w1e, const float* __restrict__ encout,
    const float* __restrict__ l2W, const float* __restrict__ l2b,
    const float* __restrict__ l3W, const float* __restrict__ l3b,
    const float* __restrict__ Vatt, const float* __restrict__ embdec,
    const float* __restrict__ dWih, const float* __restrict__ dWhh,
    const float* __restrict__ dbih, const float* __restrict__ dbhh,
    const float* __restrict__ embT, const float* __restrict__ outb,
    float* __restrict__ out) {
  const int wg = blockIdx.x, tid = threadIdx.x;
  __shared__ __align__(16) float smem[14400];
  unsigned tgt = 0;

  for (int t = 0; t < 32; ++t) {
    const int cur = t & 1;
    float* hc = dech + cur * 38400;
    float* hn = dech + (cur ^ 1) * 38400;

    // ---- phase 1: attention + x build (wg < 64, one WG per batch)
    if (wg < 64) {
      const int b = wg;
      float* h1s = smem;
      float* w2h = smem + 304;
      float* eXa = smem + 608;
      float* aa  = smem + 1424;
      float* red = smem + 1552;
      ull* redb  = (ull*)(smem + 1680);

      redb[tid] = (t > 0 && tid < 250) ? atl64(&bests[(size_t)tid * 64 + b]) : 0ULL;
      for (int i = tid; i < 300; i += 256) h1s[i] = atl(hc + 19200 + b * 300 + i);
      __syncthreads();
      for (int s = 128; s > 0; s >>= 1) {
        if (tid < s) redb[tid] = umax64(redb[tid], redb[tid + s]);
        __syncthreads();
      }
      const int ib = (t > 0) ? (int)(~(unsigned)(redb[0] & 0xFFFFFFFFULL)) : 0;

      for (int m = tid; m < 300; m += 256) {
        const float4* wr = (const float4*)(l2W + (size_t)m * 300);
        const float4* hr = (const float4*)h1s;
        float acc = l2b[m];
        for (int q = 0; q < 75; ++q) acc += dot4f(wr[q], hr[q]);
        w2h[m] = acc;
      }
      __syncthreads();

      if (tid < 128) {
        const float4* wp = (const float4*)(w1e + ((size_t)(tid << 6) + b) * 300);
        const float4* vp = (const float4*)Vatt;
        const float4* hp = (const float4*)w2h;
        float acc = 0.f;
        for (int q = 0; q < 75; ++q) {
          float4 w = wp[q], h = hp[q], v = vp[q];
          acc += tanhf(w.x + h.x) * v.x + tanhf(w.y + h.y) * v.y +
                 tanhf(w.z + h.z) * v.z + tanhf(w.w + h.w) * v.w;
        }
        aa[tid] = acc;
        red[tid] = acc;
      }
      __syncthreads();
      for (int s = 64; s > 0; s >>= 1) {
        if (tid < s) red[tid] = fmaxf(red[tid], red[tid + s]);
        __syncthreads();
      }
      float mx = red[0];
      __syncthreads();
      if (tid < 128) {
        float ex = expf(aa[tid] - mx);
        aa[tid] = ex;
        red[tid] = ex;
      }
      __syncthreads();
      for (int s = 64; s > 0; s >>= 1) {
        if (tid < s) red[tid] += red[tid + s];
        __syncthreads();
      }
      float inv = 1.0f / red[0];
      __syncthreads();
      if (tid < 128) aa[tid] *= inv;
      for (int d = tid; d < 300; d += 256) eXa[d] = embdec[(size_t)ib * 300 + d];
      __syncthreads();

      for (int d = tid; d < 512; d += 256) {
        float acc = 0.f;
        for (int s = 0; s < 128; ++s)
          acc += aa[s] * encout[((size_t)(s << 6) + b) * 512 + d];
        eXa[300 + d] = acc;
      }
      __syncthreads();

      for (int m = tid; m < 300; m += 256) {
        const float4* wr = (const float4*)(l3W + (size_t)m * 812);
        const float4* xr = (const float4*)eXa;
        float acc = l3b[m];
        for (int q = 0; q < 203; ++q) acc += dot4f(wr[q], xr[q]);
        atsf(&xdec[b * 300 + m], acc);
      }
    }
    gbar(flags, wg, ++tgt, tid);

    // ---- phase 2: GRU cell 0
    if (wg < 76)
      gru_at(wg, tid, xdec, hc, hn, nullptr, dWih, dWhh, dbih, dbhh,
             smem, smem + 4800);
    gbar(flags, wg, ++tgt, tid);

    // ---- phase 3: GRU cell 1 (+h1T)
    if (wg < 76)
      gru_at(wg, tid, hn, hc + 19200, hn + 19200, h1T,
             dWih + 270000, dWhh + 270000, dbih + 900, dbhh + 900,
             smem, smem + 4800);
    gbar(flags, wg, ++tgt, tid);

    // ---- phase 4: logits + fused argmax partials (wg < 250, 128 v-cols each)
    if (wg < 250) {
      const int v0 = wg * 128;
      const int vq = tid & 31, bo = tid >> 5;
      float acc[8][4];
#pragma unroll
      for (int i = 0; i < 8; ++i)
#pragma unroll
        for (int j = 0; j < 4; ++j) acc[i][j] = 0.f;
      float* hch = smem;         // [75][64]
      float* et  = smem + 4800;  // [75][128]
      for (int kc = 0; kc < 4; ++kc) {
        __syncthreads();
        for (int i = tid; i < 4800; i += 256) hch[i] = atl(h1T + kc * 4800 + i);
        for (int i = tid; i < 2400; i += 256) {
          int row = i >> 5, c4 = (i & 31) << 2;
          *(float4*)&et[(row << 7) + c4] =
              *(const float4*)(embT + (size_t)(kc * 75 + row) * 32000 + v0 + c4);
        }
        __syncthreads();
        for (int k = 0; k < 75; ++k) {
          float hv[8];
          *(float4*)&hv[0] = *(const float4*)&hch[(k << 6) + (bo << 3)];
          *(float4*)&hv[4] = *(const float4*)&hch[(k << 6) + (bo << 3) + 4];
          float4 ev = *(const float4*)&et[(k << 7) + (vq << 2)];
#pragma unroll
          for (int i = 0; i < 8; ++i) {
            acc[i][0] += hv[i] * ev.x;
            acc[i][1] += hv[i] * ev.y;
            acc[i][2] += hv[i] * ev.z;
            acc[i][3] += hv[i] * ev.w;
          }
        }
      }
      float4 bo4 = *(const float4*)(outb + v0 + (vq << 2));
      float* outp = out + (size_t)t * 2048000;
      float* sacc = smem;  // [128 v][64 b], reuse after loops
      __syncthreads();
#pragma unroll
      for (int i = 0; i < 8; ++i) {
        const int b = (bo << 3) + i;
        float4 r;
        r.x = acc[i][0] + bo4.x; r.y = acc[i][1] + bo4.y;
        r.z = acc[i][2] + bo4.z; r.w = acc[i][3] + bo4.w;
        *(float4*)(outp + (size_t)b * 32000 + v0 + (vq << 2)) = r;
        sacc[((vq << 2) + 0) * 64 + b] = r.x;
        sacc[((vq << 2) + 1) * 64 + b] = r.y;
        sacc[((vq << 2) + 2) * 64 + b] = r.z;
        sacc[((vq << 2) + 3) * 64 + b] = r.w;
      }
      __syncthreads();
      if (tid < 64) {
        ull best = 0ULL;
#pragma unroll 4
        for (int v = 0; v < 128; ++v)
          best = umax64(best, packmax(sacc[v * 64 + tid], v0 + v));
        ats64(&bests[(size_t)wg * 64 + tid], best);
      }
    }
    if (t < 31) gbar(flags, wg, ++tgt, tid);
  }
}

extern "C" void kernel_launch(void* const* d_in, const int* in_sizes, int n_in,
                              void* d_out_v, int out_size, void* d_ws, size_t ws_size,
                              hipStream_t stream) {
  (void)in_sizes; (void)n_in; (void)out_size; (void)ws_size;
  const float* emb_enc = (const float*)d_in[0];
  const float* eWih0   = (const float*)d_in[1];
  const float* eWhh0   = (const float*)d_in[2];
  const float* ebih0   = (const float*)d_in[3];
  const float* ebhh0   = (const float*)d_in[4];
  const float* eWih1   = (const float*)d_in[5];
  const float* eWhh1   = (const float*)d_in[6];
  const float* ebih1   = (const float*)d_in[7];
  const float* ebhh1   = (const float*)d_in[8];
  const float* Wout    = (const float*)d_in[9];
  const float* emb_dec = (const float*)d_in[10];
  const float* dWih    = (const float*)d_in[11];
  const float* dWhh    = (const float*)d_in[12];
  const float* dbih    = (const float*)d_in[13];
  const float* dbhh    = (const float*)d_in[14];
  const float* W1      = (const float*)d_in[15];
  const float* l2W     = (const float*)d_in[16];
  const float* l2b     = (const float*)d_in[17];
  const float* l3W     = (const float*)d_in[18];
  const float* l3b     = (const float*)d_in[19];
  const float* Vatt    = (const float*)d_in[20];
  const float* outb    = (const float*)d_in[21];
  const int* inp       = (const int*)d_in[22];
  float* d_out = (float*)d_out_v;

  float* ws = (float*)d_ws;
  size_t off = 0;
  auto take = [&](size_t n) { float* p = ws + off; off += (n + 3) & ~(size_t)3; return p; };
  float* embT   = take((size_t)300 * 32000);
  float* encout = take((size_t)8192 * 512);
  float* w1e    = take((size_t)8192 * 300);
  float* W1T    = take((size_t)300 * 512);
  float* hcat   = take((size_t)128 * 512);
  float* dech   = take((size_t)2 * 2 * 64 * 300);
  float* h1T    = take((size_t)300 * 64);
  float* xdec   = take((size_t)64 * 300);
  ull* bests    = (ull*)take((size_t)250 * 64 * 2);
  unsigned* flags = (unsigned*)take((size_t)256 * 32);

  // encoder scratch in d_out (dead before decoder writes)
  float* emb  = d_out;              // 2,457,600
  float* gi0f = emb + 2457600;      // 6,291,456 each
  float* gi0b = gi0f + 6291456;
  float* x1   = gi0b + 6291456;     // 4,194,304
  float* gi1f = x1 + 4194304;
  float* gi1b = gi1f + 6291456;     // ends at 31,817,728
  float* W2L0 = d_out + 33554432;   // 393,216 floats each
  float* W2L1 = W2L0 + 393216;

  hipMemsetAsync(flags, 0, 256 * 32 * sizeof(unsigned), stream);

  k_embed<<<2400, 256, 0, stream>>>((const float4*)emb_enc, inp, (float4*)emb);
  k_transpose<<<dim3(10, 16), 256, 0, stream>>>(W1, W1T, 512, 300);
  k_transpose<<<dim3(10, 1000), 256, 0, stream>>>(emb_dec, embT, 32000, 300);
  k_packW<<<768, 256, 0, stream>>>(eWhh0, W2L0);
  k_packW<<<768, 256, 0, stream>>>(eWhh1, W2L1);

  // encoder layer 0
  k_gemm128<<<dim3(64, 6), 256, 0, stream>>>(emb, eWih0, ebih0, gi0f, 8192, 768, 300);
  k_gemm128<<<dim3(64, 6), 256, 0, stream>>>(emb, eWih0 + 230400, ebih0 + 768, gi0b, 8192, 768, 300);
  k_enc_rec<<<dim3(32, 2), 256, 0, stream>>>(gi0f, gi0b, W2L0, ebhh0, x1);

  // encoder layer 1
  k_gemm128<<<dim3(64, 6), 256, 0, stream>>>(x1, eWih1, ebih1, gi1f, 8192, 768, 512);
  k_gemm128<<<dim3(64, 6), 256, 0, stream>>>(x1, eWih1 + 393216, ebih1 + 768, gi1b, 8192, 768, 512);
  k_enc_rec<<<dim3(32, 2), 256, 0, stream>>>(gi1f, gi1b, W2L1, ebhh1, encout);

  // encoder epilogue
  k_hcat<<<256, 256, 0, stream>>>(x1, encout, hcat);
  k_gemm128<<<dim3(1, 3), 256, 0, stream>>>(hcat, Wout, nullptr, dech, 128, 300, 512);
  k_gemm128<<<dim3(64, 3), 256, 0, stream>>>(encout, W1T, nullptr, w1e, 8192, 300, 512);

  // persistent decoder: all 32 steps in one dispatch
  k_dec_all<<<256, 256, 0, stream>>>(dech, h1T, xdec, bests, flags,
                                     w1e, encout, l2W, l2b, l3W, l3b,
                                     Vatt, emb_dec, dWih, dWhh, dbih, dbhh,
                                     embT, outb, d_out);
}

// Round 7
// 10919.486 us; speedup vs baseline: 1.1748x; 1.0099x over previous
//
#include <hip/hip_runtime.h>
#include <math.h>

// Seq2SeqRNN fp32.
// Encoder: sync-free persistent recurrence (r6, unchanged).
// Decoder r7: ONE persistent kernel, 256 WGs (1/CU, 157KB LDS forces it).
//  - counting barrier: single fetch_add counter, tid0-only poll (was: 65536
//    spinning threads on 256 flags = coherence-point flood = 55us/barrier).
//  - GRU weights LDS-persistent per WG role (loaded once, 32 steps reuse).
//  - read-only data (l2W/l3W/w1e/encout/embT/embdec/outb) via NORMAL loads
//    (L2-resident across steps; stale-safe because never written in-kernel).
//  - bypass atomics only for cross-phase state: dech/xdec/h1T/bests.

typedef unsigned long long ull;
typedef float v2f __attribute__((ext_vector_type(2)));

#define DINL static __device__ __forceinline__

DINL float sigm(float x) { return 1.0f / (1.0f + expf(-x)); }
DINL float dot4f(float4 a, float4 b) { return a.x*b.x + a.y*b.y + a.z*b.z + a.w*b.w; }

DINL ull packmax(float x, int v) {
  unsigned u = __float_as_uint(x);
  u = (u & 0x80000000u) ? ~u : (u | 0x80000000u);
  return ((ull)u << 32) | (unsigned)(~v);  // ties -> smaller v wins
}
DINL ull umax64(ull a, ull b) { return a > b ? a : b; }

DINL float atl(const float* p) {
  unsigned u = __hip_atomic_load((const unsigned*)p, __ATOMIC_RELAXED,
                                 __HIP_MEMORY_SCOPE_AGENT);
  return __uint_as_float(u);
}
DINL void atsf(float* p, float v) {
  __hip_atomic_exchange((unsigned*)p, __float_as_uint(v), __ATOMIC_RELAXED,
                        __HIP_MEMORY_SCOPE_AGENT);
}
DINL ull atl64(const ull* p) {
  return __hip_atomic_load(p, __ATOMIC_RELAXED, __HIP_MEMORY_SCOPE_AGENT);
}
DINL void ats64(ull* p, ull v) {
  __hip_atomic_exchange(p, v, __ATOMIC_RELAXED, __HIP_MEMORY_SCOPE_AGENT);
}

// counting grid barrier: one fetch_add + tid0-only poll. grid = 256 WGs exactly.
DINL void gbar(unsigned* cnt, unsigned target, int tid) {
  asm volatile("s_waitcnt vmcnt(0)" ::: "memory");
  __syncthreads();
  if (tid == 0) {
    __hip_atomic_fetch_add(cnt, 1u, __ATOMIC_RELAXED, __HIP_MEMORY_SCOPE_AGENT);
    while (__hip_atomic_load(cnt, __ATOMIC_RELAXED, __HIP_MEMORY_SCOPE_AGENT) < target)
      __builtin_amdgcn_s_sleep(4);
  }
  __syncthreads();
}

// ---------------- embedding gather (300 = 75 float4)
__global__ __launch_bounds__(256) void k_embed(const float4* __restrict__ E,
                                               const int* __restrict__ inp,
                                               float4* __restrict__ out) {
  int i = blockIdx.x * 256 + threadIdx.x;
  if (i >= 8192 * 75) return;
  int row = i / 75, q = i - row * 75;
  out[i] = E[(size_t)inp[row] * 75 + q];
}

// ---------------- transpose B[c*R+r] = A[r*C+c]
__global__ __launch_bounds__(256) void k_transpose(const float* __restrict__ A,
                                                   float* __restrict__ B, int R, int C) {
  __shared__ float tile[32][33];
  int c0 = blockIdx.x * 32, r0 = blockIdx.y * 32;
  int tx = threadIdx.x & 31, ty = threadIdx.x >> 5;
  for (int i = 0; i < 32; i += 8) {
    int r = r0 + ty + i, c = c0 + tx;
    if (r < R && c < C) tile[ty + i][tx] = A[(size_t)r * C + c];
  }
  __syncthreads();
  for (int i = 0; i < 32; i += 8) {
    int c = c0 + ty + i, r = r0 + tx;
    if (c < C && r < R) B[(size_t)c * R + r] = tile[tx][ty + i];
  }
}

// ---------------- pack Whh[2][768][256] -> W2[2][128 kp][768 gc][2]
__global__ __launch_bounds__(256) void k_packW(const float* __restrict__ Whh,
                                               float* __restrict__ W2) {
  int i = blockIdx.x * 256 + threadIdx.x;
  if (i >= 196608) return;
  int d = i / 98304, r = i - d * 98304, kp = r / 768, gc = r - kp * 768;
  const float* src = Whh + (size_t)d * 196608 + (size_t)gc * 256 + kp * 2;
  float* dst = W2 + (size_t)i * 2;
  dst[0] = src[0];
  dst[1] = src[1];
}

// ---------------- fp32 GEMM-NT: C[n,m] = sum_k A[n,k]*B[m,k] + bias[m]
__global__ __launch_bounds__(256) void k_gemm128(const float* __restrict__ A,
                                                 const float* __restrict__ B,
                                                 const float* __restrict__ bias,
                                                 float* __restrict__ C,
                                                 int N, int M, int K) {
  __shared__ float As[8][132];
  __shared__ float Bs[8][132];
  const int tid = threadIdx.x;
  const int bn = blockIdx.x * 128, bm = blockIdx.y * 128;
  const int tn = (tid >> 4) << 3, tm = (tid & 15) << 3;
  const int r = tid & 127;
  const bool isB = tid >= 128;
  const float* src = isB ? (B + (size_t)(bm + r) * K) : (A + (size_t)(bn + r) * K);
  const bool rowok = isB ? (bm + r < M) : (bn + r < N);
  float acc[8][8] = {};
  for (int k0 = 0; k0 < K; k0 += 8) {
    float v[8];
    if (rowok && k0 + 8 <= K) {
      float4 p0 = *(const float4*)(src + k0);
      float4 p1 = *(const float4*)(src + k0 + 4);
      v[0]=p0.x; v[1]=p0.y; v[2]=p0.z; v[3]=p0.w;
      v[4]=p1.x; v[5]=p1.y; v[6]=p1.z; v[7]=p1.w;
    } else {
#pragma unroll
      for (int j = 0; j < 8; ++j) v[j] = (rowok && k0 + j < K) ? src[k0 + j] : 0.0f;
    }
    float (*dst)[132] = isB ? Bs : As;
#pragma unroll
    for (int j = 0; j < 8; ++j) dst[j][r] = v[j];
    __syncthreads();
#pragma unroll
    for (int kk = 0; kk < 8; ++kk) {
      float a[8], b[8];
      *(float4*)&a[0] = *(const float4*)&As[kk][tn];
      *(float4*)&a[4] = *(const float4*)&As[kk][tn + 4];
      *(float4*)&b[0] = *(const float4*)&Bs[kk][tm];
      *(float4*)&b[4] = *(const float4*)&Bs[kk][tm + 4];
#pragma unroll
      for (int i = 0; i < 8; ++i)
#pragma unroll
        for (int j = 0; j < 8; ++j) acc[i][j] += a[i] * b[j];
    }
    __syncthreads();
  }
#pragma unroll
  for (int i = 0; i < 8; ++i) {
    int row = bn + tn + i;
    if (row >= N) continue;
#pragma unroll
    for (int j = 0; j < 8; ++j) {
      int col = bm + tm + j;
      if (col < M) C[(size_t)row * M + col] = acc[i][j] + (bias ? bias[col] : 0.0f);
    }
  }
}

// ---------------- sync-free encoder recurrence (r6, unchanged)
__global__ __launch_bounds__(256) void k_enc_rec(
    const float* __restrict__ giF, const float* __restrict__ giB,
    const float* __restrict__ W2, const float* __restrict__ bhh,
    float* __restrict__ y) {
  const int b0 = blockIdx.x * 2;
  const int dir = blockIdx.y;
  const int c = threadIdx.x;
  const float* gi = dir ? giB : giF;
  const v2f* Wv = (const v2f*)(W2 + (size_t)dir * 196608);
  const float* bh = bhh + dir * 768;

  __shared__ __align__(16) float hls[2][2][258];
  for (int i = c; i < 2 * 2 * 258; i += 256) ((float*)hls)[i] = 0.0f;
  __syncthreads();

  const float bhr = bh[c], bhz = bh[256 + c], bhn = bh[512 + c];
  const int tt0 = dir ? 127 : 0;
  const float* g0p = gi + (size_t)tt0 * 49152 + (size_t)b0 * 768;
  float g0r = g0p[c], g0z = g0p[256 + c], g0n = g0p[512 + c];
  float g1r = g0p[768 + c], g1z = g0p[1024 + c], g1n = g0p[1280 + c];

  for (int t = 0; t < 128; ++t) {
    const int cu = t & 1;
    float p0r = 0, p0z = 0, p0n = 0, p1r = 0, p1z = 0, p1n = 0;
    if (t < 127) {
      const int tn_ = dir ? 126 - t : t + 1;
      const float* gp = gi + (size_t)tn_ * 49152 + (size_t)b0 * 768;
      p0r = gp[c]; p0z = gp[256 + c]; p0n = gp[512 + c];
      p1r = gp[768 + c]; p1z = gp[1024 + c]; p1n = gp[1280 + c];
    }
    v2f a0r = {0,0}, a0z = {0,0}, a0n = {0,0};
    v2f a1r = {0,0}, a1z = {0,0}, a1n = {0,0};
    const float* h0p = &hls[cu][0][0];
    const float* h1p = &hls[cu][1][0];
#pragma unroll 4
    for (int kp = 0; kp < 128; ++kp) {
      v2f wr = Wv[kp * 768 + c];
      v2f wz = Wv[kp * 768 + 256 + c];
      v2f wn = Wv[kp * 768 + 512 + c];
      v2f h0 = *(const v2f*)&h0p[kp * 2];
      v2f h1 = *(const v2f*)&h1p[kp * 2];
      a0r += h0 * wr; a0z += h0 * wz; a0n += h0 * wn;
      a1r += h1 * wr; a1z += h1 * wz; a1n += h1 * wn;
    }
    float r0 = sigm(g0r + a0r.x + a0r.y + bhr);
    float z0 = sigm(g0z + a0z.x + a0z.y + bhz);
    float n0 = tanhf(g0n + r0 * (a0n.x + a0n.y + bhn));
    float h0new = (1.f - z0) * n0 + z0 * h0p[c];
    float r1 = sigm(g1r + a1r.x + a1r.y + bhr);
    float z1 = sigm(g1z + a1z.x + a1z.y + bhz);
    float n1 = tanhf(g1n + r1 * (a1n.x + a1n.y + bhn));
    float h1new = (1.f - z1) * n1 + z1 * h1p[c];
    hls[cu ^ 1][0][c] = h0new;
    hls[cu ^ 1][1][c] = h1new;
    const int tw = dir ? 127 - t : t;
    float* yp = y + (size_t)tw * 32768 + (size_t)b0 * 512 + dir * 256 + c;
    yp[0] = h0new;
    yp[512] = h1new;
    g0r = p0r; g0z = p0z; g0n = p0n; g1r = p1r; g1z = p1z; g1n = p1n;
    __syncthreads();
  }
}

// ---------------- hcat[2][64][512]
__global__ __launch_bounds__(256) void k_hcat(const float* __restrict__ x1,
                                              const float* __restrict__ encout,
                                              float* __restrict__ hcat) {
  int i = blockIdx.x * 256 + threadIdx.x;
  int l = i >> 15, r = i & 32767, b = r >> 9, d = r & 511;
  const float* src = l ? encout : x1;
  int ts = (d < 256) ? 127 : 0;
  hcat[i] = src[((size_t)(ts << 6) + b) * 512 + d];
}

// ---------------- GRU cell phase with LDS-resident weights.
// Wg[6][16][308]: gates {ir,iz,in,hr,hz,hn} for this WG's 16 cols.
DINL void gru_lds(int cch, int bch, int tid,
                  const float* __restrict__ xin, const float* __restrict__ hin,
                  float* __restrict__ hout, float* __restrict__ houtT,
                  const float* Wg, const float* biass, float* scr) {
  float* xs = scr;           // [16][300]
  float* hs = scr + 4800;    // [16][300]
  const int b0 = bch * 16;
  for (int i = tid; i < 4800; i += 256) {
    int row = i / 300, q = i - row * 300;
    xs[i] = atl(xin + (size_t)(b0 + row) * 300 + q);
    hs[i] = atl(hin + (size_t)(b0 + row) * 300 + q);
  }
  __syncthreads();
  const int cl = tid & 15, bl = tid >> 4;
  const int c = cch * 16 + cl, bq = b0 + bl;
  if (c < 300) {
    float gir = biass[cl],      giz = biass[16 + cl], gin = biass[32 + cl];
    float ghr = biass[48 + cl], ghz = biass[64 + cl], ghn = biass[80 + cl];
    const float4* xr = (const float4*)(xs + bl * 300);
    const float4* hr = (const float4*)(hs + bl * 300);
    const float4* w0 = (const float4*)(Wg + (0 * 16 + cl) * 308);
    const float4* w1 = (const float4*)(Wg + (1 * 16 + cl) * 308);
    const float4* w2 = (const float4*)(Wg + (2 * 16 + cl) * 308);
    const float4* w3 = (const float4*)(Wg + (3 * 16 + cl) * 308);
    const float4* w4 = (const float4*)(Wg + (4 * 16 + cl) * 308);
    const float4* w5 = (const float4*)(Wg + (5 * 16 + cl) * 308);
    for (int q = 0; q < 75; ++q) {
      float4 xv = xr[q], hv = hr[q];
      gir += dot4f(xv, w0[q]);
      giz += dot4f(xv, w1[q]);
      gin += dot4f(xv, w2[q]);
      ghr += dot4f(hv, w3[q]);
      ghz += dot4f(hv, w4[q]);
      ghn += dot4f(hv, w5[q]);
    }
    float r = sigm(gir + ghr), z = sigm(giz + ghz);
    float n = tanhf(gin + r * ghn);
    float hnew = (1.f - z) * n + z * hs[bl * 300 + c];
    atsf(&hout[(size_t)bq * 300 + c], hnew);
    if (houtT) atsf(&houtT[(size_t)c * 64 + bq], hnew);
  }
  __syncthreads();  // protect scr reuse by next phase
}

// ---------------- persistent decoder: all 32 steps, 256 WGs (1/CU).
__global__ __launch_bounds__(256) void k_dec_all(
    float* __restrict__ dech, float* __restrict__ h1T, float* __restrict__ xdec,
    ull* __restrict__ bests, unsigned* __restrict__ cnt,
    const float* __restrict__ w1e, const float* __restrict__ encout,
    const float* __restrict__ l2W, const float* __restrict__ l2b,
    const float* __restrict__ l3W, const float* __restrict__ l3b,
    const float* __restrict__ Vatt, const float* __restrict__ embdec,
    const float* __restrict__ dWih, const float* __restrict__ dWhh,
    const float* __restrict__ dbih, const float* __restrict__ dbhh,
    const float* __restrict__ embT, const float* __restrict__ outb,
    float* __restrict__ out) {
  const int wg = blockIdx.x, tid = threadIdx.x;
  __shared__ __align__(16) float Wg[6 * 16 * 308];   // 118,272 B
  __shared__ __align__(16) float scr[9600];          // 38,400 B
  __shared__ float biass[96];

  // ---- one-time: load this WG's GRU weight slice into LDS
  int grole = -1, gcell = 0;
  if (wg < 76) { grole = wg; gcell = 0; }
  else if (wg < 152) { grole = wg - 76; gcell = 1; }
  const int cch = (grole >= 0) ? grole % 19 : 0;
  const int bch = (grole >= 0) ? grole / 19 : 0;
  if (grole >= 0) {
    const float* Wih = dWih + gcell * 270000;
    const float* Whh = dWhh + gcell * 270000;
    for (int i = tid; i < 96 * 300; i += 256) {
      int r = i / 300, k = i - r * 300;
      int g = r >> 4, cl = r & 15;
      int c = cch * 16 + cl;
      float v = 0.f;
      if (c < 300)
        v = (g < 3) ? Wih[(size_t)(g * 300 + c) * 300 + k]
                    : Whh[(size_t)((g - 3) * 300 + c) * 300 + k];
      Wg[(g * 16 + cl) * 308 + k] = v;
    }
    if (tid < 96) {
      int g = tid >> 4, cl = tid & 15;
      int c = cch * 16 + cl;
      float v = 0.f;
      if (c < 300)
        v = (g < 3) ? dbih[gcell * 900 + g * 300 + c]
                    : dbhh[gcell * 900 + (g - 3) * 300 + c];
      biass[tid] = v;
    }
  }
  __syncthreads();

  unsigned tgt = 0;
  for (int t = 0; t < 32; ++t) {
    const int cur = t & 1;
    float* hc = dech + cur * 38400;
    float* hn = dech + (cur ^ 1) * 38400;

    // ---- phase 1: attention + x build (wg < 64)
    if (wg < 64) {
      const int b = wg;
      float* h1s = scr;
      float* w2h = scr + 304;
      float* eXa = scr + 608;
      float* aa  = scr + 1424;
      float* red = scr + 1552;
      ull* redb  = (ull*)(scr + 1680);

      if (tid < 128) {
        ull m = 0ULL;
        if (t > 0) {
          m = atl64(&bests[(size_t)tid * 64 + b]);
          if (tid + 128 < 250) m = umax64(m, atl64(&bests[(size_t)(tid + 128) * 64 + b]));
        }
        redb[tid] = m;
      }
      for (int i = tid; i < 300; i += 256) h1s[i] = atl(hc + 19200 + b * 300 + i);
      __syncthreads();
      for (int s = 64; s > 0; s >>= 1) {
        if (tid < s) redb[tid] = umax64(redb[tid], redb[tid + s]);
        __syncthreads();
      }
      const int ib = (t > 0) ? (int)(~(unsigned)(redb[0] & 0xFFFFFFFFULL)) : 0;

      for (int m = tid; m < 300; m += 256) {
        const float4* wr = (const float4*)(l2W + (size_t)m * 300);
        const float4* hr = (const float4*)h1s;
        float acc = l2b[m];
        for (int q = 0; q < 75; ++q) acc += dot4f(wr[q], hr[q]);
        w2h[m] = acc;
      }
      __syncthreads();

      if (tid < 128) {
        const float4* wp = (const float4*)(w1e + ((size_t)(tid << 6) + b) * 300);
        const float4* vp = (const float4*)Vatt;
        const float4* hp = (const float4*)w2h;
        float acc = 0.f;
        for (int q = 0; q < 75; ++q) {
          float4 w = wp[q], h = hp[q], v = vp[q];
          acc += tanhf(w.x + h.x) * v.x + tanhf(w.y + h.y) * v.y +
                 tanhf(w.z + h.z) * v.z + tanhf(w.w + h.w) * v.w;
        }
        aa[tid] = acc;
        red[tid] = acc;
      }
      __syncthreads();
      for (int s = 64; s > 0; s >>= 1) {
        if (tid < s) red[tid] = fmaxf(red[tid], red[tid + s]);
        __syncthreads();
      }
      float mx = red[0];
      __syncthreads();
      if (tid < 128) {
        float ex = expf(aa[tid] - mx);
        aa[tid] = ex;
        red[tid] = ex;
      }
      __syncthreads();
      for (int s = 64; s > 0; s >>= 1) {
        if (tid < s) red[tid] += red[tid + s];
        __syncthreads();
      }
      float inv = 1.0f / red[0];
      __syncthreads();
      if (tid < 128) aa[tid] *= inv;
      for (int d = tid; d < 300; d += 256) eXa[d] = embdec[(size_t)ib * 300 + d];
      __syncthreads();

      for (int d = tid; d < 512; d += 256) {
        float acc = 0.f;
        for (int s = 0; s < 128; ++s)
          acc += aa[s] * encout[((size_t)(s << 6) + b) * 512 + d];
        eXa[300 + d] = acc;
      }
      __syncthreads();

      for (int m = tid; m < 300; m += 256) {
        const float4* wr = (const float4*)(l3W + (size_t)m * 812);
        const float4* xr = (const float4*)eXa;
        float acc = l3b[m];
        for (int q = 0; q < 203; ++q) acc += dot4f(wr[q], xr[q]);
        atsf(&xdec[b * 300 + m], acc);
      }
      __syncthreads();
    }
    gbar(cnt, 256u * (++tgt), tid);

    // ---- phase 2: GRU cell 0 (wg < 76, weights resident)
    if (wg < 76)
      gru_lds(cch, bch, tid, xdec, hc, hn, nullptr, Wg, biass, scr);
    gbar(cnt, 256u * (++tgt), tid);

    // ---- phase 3: GRU cell 1 (wg 76..151, weights resident)
    if (wg >= 76 && wg < 152)
      gru_lds(cch, bch, tid, hn, hc + 19200, hn + 19200, h1T, Wg, biass, scr);
    gbar(cnt, 256u * (++tgt), tid);

    // ---- phase 4: logits + argmax partials (wg < 250, 128 v-cols each)
    if (wg < 250) {
      const int v0 = wg * 128;
      const int vq = tid & 31, bo = tid >> 5;
      float acc[8][4];
#pragma unroll
      for (int i = 0; i < 8; ++i)
#pragma unroll
        for (int j = 0; j < 4; ++j) acc[i][j] = 0.f;
      float* hch = scr;  // [75][64]
      for (int kc = 0; kc < 4; ++kc) {
        __syncthreads();
        for (int i = tid; i < 4800; i += 256) hch[i] = atl(h1T + kc * 4800 + i);
        __syncthreads();
        const float* eb = embT + (size_t)kc * 75 * 32000 + v0 + (vq << 2);
        for (int k = 0; k < 75; ++k) {
          float4 ev = *(const float4*)(eb + (size_t)k * 32000);
          float hv[8];
          *(float4*)&hv[0] = *(const float4*)&hch[(k << 6) + (bo << 3)];
          *(float4*)&hv[4] = *(const float4*)&hch[(k << 6) + (bo << 3) + 4];
#pragma unroll
          for (int i = 0; i < 8; ++i) {
            acc[i][0] += hv[i] * ev.x;
            acc[i][1] += hv[i] * ev.y;
            acc[i][2] += hv[i] * ev.z;
            acc[i][3] += hv[i] * ev.w;
          }
        }
      }
      float4 bo4 = *(const float4*)(outb + v0 + (vq << 2));
      float* outp = out + (size_t)t * 2048000;
      float* sacc = scr;  // [128 v][65] padded
      __syncthreads();
#pragma unroll
      for (int i = 0; i < 8; ++i) {
        const int b = (bo << 3) + i;
        float4 r;
        r.x = acc[i][0] + bo4.x; r.y = acc[i][1] + bo4.y;
        r.z = acc[i][2] + bo4.z; r.w = acc[i][3] + bo4.w;
        *(float4*)(outp + (size_t)b * 32000 + v0 + (vq << 2)) = r;
        sacc[((vq << 2) + 0) * 65 + b] = r.x;
        sacc[((vq << 2) + 1) * 65 + b] = r.y;
        sacc[((vq << 2) + 2) * 65 + b] = r.z;
        sacc[((vq << 2) + 3) * 65 + b] = r.w;
      }
      __syncthreads();
      if (tid < 64) {
        ull best = 0ULL;
#pragma unroll 4
        for (int v = 0; v < 128; ++v)
          best = umax64(best, packmax(sacc[v * 65 + tid], v0 + v));
        ats64(&bests[(size_t)wg * 64 + tid], best);
      }
      __syncthreads();
    }
    if (t < 31) gbar(cnt, 256u * (++tgt), tid);
  }
}

extern "C" void kernel_launch(void* const* d_in, const int* in_sizes, int n_in,
                              void* d_out_v, int out_size, void* d_ws, size_t ws_size,
                              hipStream_t stream) {
  (void)in_sizes; (void)n_in; (void)out_size; (void)ws_size;
  const float* emb_enc = (const float*)d_in[0];
  const float* eWih0   = (const float*)d_in[1];
  const float* eWhh0   = (const float*)d_in[2];
  const float* ebih0   = (const float*)d_in[3];
  const float* ebhh0   = (const float*)d_in[4];
  const float* eWih1   = (const float*)d_in[5];
  const float* eWhh1   = (const float*)d_in[6];
  const float* ebih1   = (const float*)d_in[7];
  const float* ebhh1   = (const float*)d_in[8];
  const float* Wout    = (const float*)d_in[9];
  const float* emb_dec = (const float*)d_in[10];
  const float* dWih    = (const float*)d_in[11];
  const float* dWhh    = (const float*)d_in[12];
  const float* dbih    = (const float*)d_in[13];
  const float* dbhh    = (const float*)d_in[14];
  const float* W1      = (const float*)d_in[15];
  const float* l2W     = (const float*)d_in[16];
  const float* l2b     = (const float*)d_in[17];
  const float* l3W     = (const float*)d_in[18];
  const float* l3b     = (const float*)d_in[19];
  const float* Vatt    = (const float*)d_in[20];
  const float* outb    = (const float*)d_in[21];
  const int* inp       = (const int*)d_in[22];
  float* d_out = (float*)d_out_v;

  float* ws = (float*)d_ws;
  size_t off = 0;
  auto take = [&](size_t n) { float* p = ws + off; off += (n + 3) & ~(size_t)3; return p; };
  float* embT   = take((size_t)300 * 32000);
  float* encout = take((size_t)8192 * 512);
  float* w1e    = take((size_t)8192 * 300);
  float* W1T    = take((size_t)300 * 512);
  float* hcat   = take((size_t)128 * 512);
  float* dech   = take((size_t)2 * 2 * 64 * 300);
  float* h1T    = take((size_t)300 * 64);
  float* xdec   = take((size_t)64 * 300);
  ull* bests    = (ull*)take((size_t)250 * 64 * 2);
  unsigned* cnt = (unsigned*)take((size_t)32);

  // encoder scratch in d_out (dead before decoder writes)
  float* emb  = d_out;
  float* gi0f = emb + 2457600;
  float* gi0b = gi0f + 6291456;
  float* x1   = gi0b + 6291456;
  float* gi1f = x1 + 4194304;
  float* gi1b = gi1f + 6291456;
  float* W2L0 = d_out + 33554432;
  float* W2L1 = W2L0 + 393216;

  hipMemsetAsync(cnt, 0, 32 * sizeof(unsigned), stream);

  k_embed<<<2400, 256, 0, stream>>>((const float4*)emb_enc, inp, (float4*)emb);
  k_transpose<<<dim3(10, 16), 256, 0, stream>>>(W1, W1T, 512, 300);
  k_transpose<<<dim3(10, 1000), 256, 0, stream>>>(emb_dec, embT, 32000, 300);
  k_packW<<<768, 256, 0, stream>>>(eWhh0, W2L0);
  k_packW<<<768, 256, 0, stream>>>(eWhh1, W2L1);

  // encoder layer 0
  k_gemm128<<<dim3(64, 6), 256, 0, stream>>>(emb, eWih0, ebih0, gi0f, 8192, 768, 300);
  k_gemm128<<<dim3(64, 6), 256, 0, stream>>>(emb, eWih0 + 230400, ebih0 + 768, gi0b, 8192, 768, 300);
  k_enc_rec<<<dim3(32, 2), 256, 0, stream>>>(gi0f, gi0b, W2L0, ebhh0, x1);

  // encoder layer 1
  k_gemm128<<<dim3(64, 6), 256, 0, stream>>>(x1, eWih1, ebih1, gi1f, 8192, 768, 512);
  k_gemm128<<<dim3(64, 6), 256, 0, stream>>>(x1, eWih1 + 393216, ebih1 + 768, gi1b, 8192, 768, 512);
  k_enc_rec<<<dim3(32, 2), 256, 0, stream>>>(gi1f, gi1b, W2L1, ebhh1, encout);

  // encoder epilogue
  k_hcat<<<256, 256, 0, stream>>>(x1, encout, hcat);
  k_gemm128<<<dim3(1, 3), 256, 0, stream>>>(hcat, Wout, nullptr, dech, 128, 300, 512);
  k_gemm128<<<dim3(64, 3), 256, 0, stream>>>(encout, W1T, nullptr, w1e, 8192, 300, 512);

  // persistent decoder
  k_dec_all<<<256, 256, 0, stream>>>(dech, h1T, xdec, bests, cnt,
                                     w1e, encout, l2W, l2b, l3W, l3b,
                                     Vatt, emb_dec, dWih, dWhh, dbih, dbhh,
                                     embT, outb, d_out);
}